// Round 1
// baseline (408.419 us; speedup 1.0000x reference)
//
#include <hip/hip_runtime.h>
#include <hip/hip_bf16.h>
#include <math.h>

// ---- problem constants ----
#define BSZ 32
#define SL 256
#define WPL 4
#define NP 320
#define WD 768
#define PD 64
#define RD 64
#define FD 512
#define PL 8
#define NF 128
#define NIN 896          // WD + 2*PD
#define ES_STRIDE 513    // 2*SL + 1
#define NCAT 1152        // 9 taps * NF
#define MROWS (BSZ * SL) // 8192

// ============================================================
// K1: node_in[b*SL+s][0:896] = [word(768) | pos_emb(64) | pathdepth_emb(64)]
// ============================================================
__global__ __launch_bounds__(256) void build_node_in(
    const float* __restrict__ bert, const int* __restrict__ wgi,
    const int* __restrict__ pos, const int* __restrict__ path,
    const float* __restrict__ pos_emb, const float* __restrict__ pd_emb,
    float* __restrict__ node_in)
{
    const int bs = blockIdx.x;     // 0..8191
    const int b = bs / SL;
    const int tid = threadIdx.x;
    const int* gi = wgi + (size_t)bs * WPL;
    const int i0 = gi[0], i1 = gi[1], i2 = gi[2], i3 = gi[3];
    const int npc = (i0 != 0) + (i1 != 0) + (i2 != 0) + (i3 != 0);
    const float inv = 1.0f / (float)(npc > 1 ? npc : 1);
    const float* r0 = bert + ((size_t)b * NP + (i0 - 1)) * WD;
    const float* r1 = bert + ((size_t)b * NP + (i1 - 1)) * WD;
    const float* r2 = bert + ((size_t)b * NP + (i2 - 1)) * WD;
    const float* r3 = bert + ((size_t)b * NP + (i3 - 1)) * WD;
    float* out = node_in + (size_t)bs * NIN;
    for (int c = tid; c < WD; c += 256) {
        float v = 0.f;
        if (i0) v += r0[c];
        if (i1) v += r1[c];
        if (i2) v += r2[c];
        if (i3) v += r3[c];
        out[c] = v * inv;
    }
    if (tid < PD) {
        out[WD + tid] = pos_emb[pos[bs] * PD + tid];
    } else if (tid < 2 * PD) {
        const int* pp = path + (size_t)bs * PL;
        int pd = 0;
#pragma unroll
        for (int l = 0; l < PL; ++l) pd += (pp[l] != 0);
        out[WD + PD + (tid - PD)] = pd_emb[pd * PD + (tid - PD)];
    }
}

// ============================================================
// K2: Ut[r][d] = sum_j bilin_W[d][j]*deprel_emb[r][j]  (r<64, d<1024)
//     v[d]    = sum_j bilin_W[d][j]*ext_rel[j]         (d<512)
// ============================================================
__global__ __launch_bounds__(256) void build_U(
    const float* __restrict__ bilin_W, const float* __restrict__ deprel_emb,
    const float* __restrict__ ext_rel, float* __restrict__ Ut, float* __restrict__ v)
{
    const int idx = blockIdx.x * 256 + threadIdx.x;
    if (idx < 64 * 1024) {
        const int r = idx >> 10, d = idx & 1023;
        float s = 0.f;
#pragma unroll
        for (int j = 0; j < RD; ++j) s += bilin_W[d * RD + j] * deprel_emb[r * RD + j];
        Ut[idx] = s;
    } else if (idx < 64 * 1024 + FD) {
        const int d = idx - 64 * 1024;
        float s = 0.f;
#pragma unroll
        for (int j = 0; j < RD; ++j) s += bilin_W[d * RD + j] * ext_rel[j];
        v[d] = s;
    }
}

// ============================================================
// K3: Wcat[k][t*128+f], taps t: 0-1 -> W_k2, 2-4 -> W_k3, 5-8 -> W_k4
// ============================================================
__global__ __launch_bounds__(256) void build_Wcat(
    const float* __restrict__ W2, const float* __restrict__ W3,
    const float* __restrict__ W4, float* __restrict__ Wcat)
{
    const int idx = blockIdx.x * 256 + threadIdx.x;
    if (idx >= FD * NCAT) return;
    const int k = idx / NCAT;
    const int c = idx % NCAT;
    const int t = c >> 7, f = c & 127;
    float val;
    if (t < 2)      val = W2[((size_t)t * FD + k) * NF + f];
    else if (t < 5) val = W3[((size_t)(t - 2) * FD + k) * NF + f];
    else            val = W4[((size_t)(t - 5) * FD + k) * NF + f];
    Wcat[idx] = val;
}

// ============================================================
// K4/K7: tiled f32 GEMM  C[MxN] = act(A[MxK] @ B[KxN] + bias)
// 64x64 tile, 256 threads, each 4x4. M%64==0, N%64==0, K%16==0.
// ============================================================
#define TS 64
#define KT 16
__global__ __launch_bounds__(256) void gemm_bias_act(
    const float* __restrict__ A, const float* __restrict__ B,
    const float* __restrict__ bias, float* __restrict__ C,
    int M, int N, int K, int relu)
{
    __shared__ float As[KT][TS + 4];
    __shared__ float Bs[KT][TS + 4];
    const int tid = threadIdx.x;
    const int tx = tid & 15, ty = tid >> 4;
    const int col0 = blockIdx.x * TS, row0 = blockIdx.y * TS;
    float acc[4][4] = {};
    for (int k0 = 0; k0 < K; k0 += KT) {
#pragma unroll
        for (int e = tid; e < TS * KT; e += 256) {
            const int m = e >> 4, k = e & 15;
            As[k][m] = A[(size_t)(row0 + m) * K + k0 + k];
        }
#pragma unroll
        for (int e = tid; e < KT * TS; e += 256) {
            const int k = e >> 6, n = e & 63;
            Bs[k][n] = B[(size_t)(k0 + k) * N + col0 + n];
        }
        __syncthreads();
#pragma unroll
        for (int kk = 0; kk < KT; ++kk) {
            const float4 a4 = *reinterpret_cast<const float4*>(&As[kk][ty * 4]);
            const float4 b4 = *reinterpret_cast<const float4*>(&Bs[kk][tx * 4]);
            const float av[4] = {a4.x, a4.y, a4.z, a4.w};
            const float bv[4] = {b4.x, b4.y, b4.z, b4.w};
#pragma unroll
            for (int i = 0; i < 4; ++i)
#pragma unroll
                for (int j = 0; j < 4; ++j)
                    acc[i][j] = fmaf(av[i], bv[j], acc[i][j]);
        }
        __syncthreads();
    }
#pragma unroll
    for (int i = 0; i < 4; ++i) {
        const int m = row0 + ty * 4 + i;
#pragma unroll
        for (int j = 0; j < 4; ++j) {
            const int n = col0 + tx * 4 + j;
            float vo = acc[i][j] + (bias ? bias[n] : 0.f);
            if (relu) vo = fmaxf(vo, 0.f);
            C[(size_t)m * N + n] = vo;
        }
    }
}

// ============================================================
// K5: edge scores.  One 64-lane wave per (b, n), n in [0, 2SL).
// n < SL : sigmoid(dep . Ut[dr][0:512] + node . Ut[dr][512:1024] + bb)
// n >= SL: sigmoid(node . v + bb)
// ============================================================
__global__ __launch_bounds__(256) void score_kernel(
    const float* __restrict__ node, const int* __restrict__ aspect_head,
    const int* __restrict__ deprel, const float* __restrict__ Ut,
    const float* __restrict__ v, const float* __restrict__ bilin_b,
    float* __restrict__ edge_score)
{
    const int g = blockIdx.x * 4 + (threadIdx.x >> 6);
    const int lane = threadIdx.x & 63;
    const int b = g >> 9;
    const int n = g & 511;
    float sum = 0.f;
    if (n < SL) {
        const int dr = deprel[b * SL + n];
        const int h = aspect_head[b * SL + n];
        const float* nd = node + ((size_t)b * SL + n) * FD;
        const float* uc = Ut + (size_t)dr * 1024;
        if (h != 0) {
            const float* dep = node + ((size_t)b * SL + (h - 1)) * FD;
#pragma unroll
            for (int d = lane; d < FD; d += 64) sum += dep[d] * uc[d];
        }
#pragma unroll
        for (int d = lane; d < FD; d += 64) sum += nd[d] * uc[FD + d];
    } else {
        const float* nd = node + ((size_t)b * SL + (n - SL)) * FD;
#pragma unroll
        for (int d = lane; d < FD; d += 64) sum += nd[d] * v[d];
    }
#pragma unroll
    for (int off = 32; off > 0; off >>= 1) sum += __shfl_xor(sum, off, 64);
    if (lane == 0) {
        const float sc = 1.f / (1.f + expf(-(sum + bilin_b[0])));
        edge_score[b * ES_STRIDE + 1 + n] = sc;
        if (n == 0) edge_score[b * ES_STRIDE] = 1.0f;
    }
}

// ============================================================
// K6: nw[b][s] = masked prod over path of edge_score; weight_norm[b] = sum_s
// ============================================================
__global__ __launch_bounds__(256) void nw_kernel(
    const float* __restrict__ edge_score, const int* __restrict__ path,
    const int* __restrict__ text_mask, const int* __restrict__ aspect_mask,
    float* __restrict__ nw, float* __restrict__ weight_norm)
{
    const int b = blockIdx.x, s = threadIdx.x;
    const float* es = edge_score + b * ES_STRIDE;
    const int* pp = path + ((size_t)b * SL + s) * PL;
    float p = 1.f;
#pragma unroll
    for (int l = 0; l < PL; ++l) p *= es[pp[l]];
    if (!(text_mask[b * SL + s] != 0 && aspect_mask[b * SL + s] == 0)) p = 0.f;
    nw[b * SL + s] = p;
    __shared__ float red[256];
    red[s] = p;
    __syncthreads();
    for (int off = 128; off > 0; off >>= 1) {
        if (s < off) red[s] += red[s + off];
        __syncthreads();
    }
    if (s == 0) weight_norm[b] = red[0];
}

// ============================================================
// K8: windowed scale + max-pool.  grid (BSZ, 3), 512 threads.
// sentence[b][w*128+f] = max_n( mean(nw[n..n+kw-1]) * sum_k Y[n+k][tap0+k][f] + bias[f] )
// ============================================================
__global__ __launch_bounds__(512) void pool_kernel(
    const float* __restrict__ Y, const float* __restrict__ nw,
    const float* __restrict__ b2, const float* __restrict__ b3,
    const float* __restrict__ b4, float* __restrict__ sentence)
{
    const int b = blockIdx.x;
    const int w = blockIdx.y;      // 0..2
    const int tid = threadIdx.x;   // 512
    const int q = tid >> 7;        // 0..3
    const int f = tid & 127;
    __shared__ float snw[SL];
    if (tid < SL) snw[tid] = nw[b * SL + tid];
    __syncthreads();
    const int kw = w + 2;
    const int tap0 = (w == 0) ? 0 : (w == 1) ? 2 : 5;
    const float* bias = (w == 0) ? b2 : (w == 1) ? b3 : b4;
    const float bf = bias[f];
    const int cn = SL - kw + 1;
    const float invk = 1.f / (float)kw;
    const float* Yb = Y + (size_t)b * SL * NCAT + (size_t)tap0 * NF + f;
    float mx = -INFINITY;
    for (int n = q; n < cn; n += 4) {
        float wsum = 0.f, acc = 0.f;
        for (int k = 0; k < kw; ++k) {
            wsum += snw[n + k];
            acc += Yb[(size_t)(n + k) * NCAT + (size_t)k * NF];
        }
        mx = fmaxf(mx, wsum * invk * acc + bf);
    }
    __shared__ float pm[4][NF];
    pm[q][f] = mx;
    __syncthreads();
    if (q == 0) {
        mx = fmaxf(fmaxf(pm[0][f], pm[1][f]), fmaxf(pm[2][f], pm[3][f]));
        sentence[(size_t)b * 384 + w * NF + f] = mx;
    }
}

// ============================================================
// K9: predicts = sentence @ fc_out_W + fc_out_b  -> out[0:96]
// ============================================================
__global__ __launch_bounds__(128) void fc_out_kernel(
    const float* __restrict__ sentence, const float* __restrict__ W,
    const float* __restrict__ bias, float* __restrict__ out)
{
    const int t = threadIdx.x;
    if (t >= BSZ * 3) return;
    const int b = t / 3, o = t % 3;
    float acc = bias[o];
    for (int i = 0; i < 384; ++i) acc = fmaf(sentence[b * 384 + i], W[i * 3 + o], acc);
    out[t] = acc;
}

// ============================================================
extern "C" void kernel_launch(void* const* d_in, const int* in_sizes, int n_in,
                              void* d_out, int out_size, void* d_ws, size_t ws_size,
                              hipStream_t stream)
{
    const float* bert      = (const float*)d_in[0];
    const int*   wgi       = (const int*)d_in[1];
    const int*   pos       = (const int*)d_in[2];
    const int*   deprel    = (const int*)d_in[3];
    const int*   path      = (const int*)d_in[4];
    const int*   ahead     = (const int*)d_in[5];
    const int*   tmask     = (const int*)d_in[6];
    const int*   amask     = (const int*)d_in[7];
    const float* pos_emb   = (const float*)d_in[8];
    const float* dre_emb   = (const float*)d_in[9];
    const float* pd_emb    = (const float*)d_in[10];
    const float* ext_rel   = (const float*)d_in[11];
    const float* fc1_W     = (const float*)d_in[12];
    const float* fc1_b     = (const float*)d_in[13];
    const float* bilin_W   = (const float*)d_in[14];
    const float* bilin_b   = (const float*)d_in[15];
    const float* W2        = (const float*)d_in[16];
    const float* b2        = (const float*)d_in[17];
    const float* W3        = (const float*)d_in[18];
    const float* b3        = (const float*)d_in[19];
    const float* W4        = (const float*)d_in[20];
    const float* b4        = (const float*)d_in[21];
    const float* fco_W     = (const float*)d_in[22];
    const float* fco_b     = (const float*)d_in[23];
    float* out = (float*)d_out;

    // workspace layout (floats). Region A holds node_in (7.34M f) then is
    // reused for Y (9.44M f) after node_in is consumed by GEMM1.
    float* regionA = (float*)d_ws;
    const size_t offA = (size_t)MROWS * NCAT;      // 9,437,184 floats
    float* node  = regionA + offA;                 // 8192*512
    float* Ut    = node + (size_t)MROWS * FD;      // 64*1024
    float* vvec  = Ut + 64 * 1024;                 // 512
    float* es    = vvec + FD;                      // 32*513
    float* nw    = es + BSZ * ES_STRIDE;           // 8192
    float* Wcat  = nw + BSZ * SL;                  // 512*1152
    float* sent  = Wcat + (size_t)FD * NCAT;       // 32*384

    float* node_in = regionA;
    float* Y = regionA;

    build_node_in<<<MROWS, 256, 0, stream>>>(bert, wgi, pos, path, pos_emb, pd_emb, node_in);
    build_U<<<258, 256, 0, stream>>>(bilin_W, dre_emb, ext_rel, Ut, vvec);
    build_Wcat<<<(FD * NCAT + 255) / 256, 256, 0, stream>>>(W2, W3, W4, Wcat);

    // node = relu(node_in @ fc1_W + fc1_b)
    gemm_bias_act<<<dim3(FD / TS, MROWS / TS), 256, 0, stream>>>(
        node_in, fc1_W, fc1_b, node, MROWS, FD, NIN, 1);

    score_kernel<<<(BSZ * 2 * SL) / 4, 256, 0, stream>>>(
        node, ahead, deprel, Ut, vvec, bilin_b, es);

    nw_kernel<<<BSZ, 256, 0, stream>>>(es, path, tmask, amask, nw, out + 96);

    // Y = node @ Wcat   (no bias/act)
    gemm_bias_act<<<dim3(NCAT / TS, MROWS / TS), 256, 0, stream>>>(
        node, Wcat, nullptr, Y, MROWS, NCAT, FD, 0);

    pool_kernel<<<dim3(BSZ, 3), 512, 0, stream>>>(Y, nw, b2, b3, b4, sent);

    fc_out_kernel<<<1, 128, 0, stream>>>(sent, fco_W, fco_b, out);
}

// Round 2
// 174.942 us; speedup vs baseline: 2.3346x; 2.3346x over previous
//
#include <hip/hip_runtime.h>
#include <hip/hip_bf16.h>
#include <math.h>

// ---- problem constants ----
#define BSZ 32
#define SL 256
#define WPL 4
#define NP 320
#define WD 768
#define PD 64
#define RD 64
#define FD 512
#define PL 8
#define NF 128
#define NIN 896          // WD + 2*PD
#define ES_STRIDE 513    // 2*SL + 1
#define NCAT 1152        // 9 taps * NF
#define MROWS (BSZ * SL) // 8192

typedef __attribute__((ext_vector_type(8))) short bf16x8;
typedef __attribute__((ext_vector_type(4))) float f32x4;
typedef unsigned short ushort_t;

__device__ __forceinline__ ushort_t f2bf(float x) {
    __hip_bfloat16 h = __float2bfloat16(x);
    return *reinterpret_cast<ushort_t*>(&h);
}
__device__ __forceinline__ float bf2f(ushort_t u) {
    return __uint_as_float(((unsigned)u) << 16);
}

// ============================================================
// K1: node_in[bs][0:896] = [word(768) | pos_emb(64) | pathdepth_emb(64)]  (bf16)
// ============================================================
__global__ __launch_bounds__(256) void build_node_in(
    const float* __restrict__ bert, const int* __restrict__ wgi,
    const int* __restrict__ pos, const int* __restrict__ path,
    const float* __restrict__ pos_emb, const float* __restrict__ pd_emb,
    ushort_t* __restrict__ node_in)
{
    const int bs = blockIdx.x;     // 0..8191
    const int b = bs / SL;
    const int tid = threadIdx.x;
    const int* gi = wgi + (size_t)bs * WPL;
    const int i0 = gi[0], i1 = gi[1], i2 = gi[2], i3 = gi[3];
    const int npc = (i0 != 0) + (i1 != 0) + (i2 != 0) + (i3 != 0);
    const float inv = 1.0f / (float)(npc > 1 ? npc : 1);
    const float* r0 = bert + ((size_t)b * NP + (i0 - 1)) * WD;
    const float* r1 = bert + ((size_t)b * NP + (i1 - 1)) * WD;
    const float* r2 = bert + ((size_t)b * NP + (i2 - 1)) * WD;
    const float* r3 = bert + ((size_t)b * NP + (i3 - 1)) * WD;
    ushort_t* out = node_in + (size_t)bs * NIN;
    for (int c = tid; c < WD; c += 256) {
        float v = 0.f;
        if (i0) v += r0[c];
        if (i1) v += r1[c];
        if (i2) v += r2[c];
        if (i3) v += r3[c];
        out[c] = f2bf(v * inv);
    }
    if (tid < PD) {
        out[WD + tid] = f2bf(pos_emb[pos[bs] * PD + tid]);
    } else if (tid < 2 * PD) {
        const int* pp = path + (size_t)bs * PL;
        int pd = 0;
#pragma unroll
        for (int l = 0; l < PL; ++l) pd += (pp[l] != 0);
        out[WD + PD + (tid - PD)] = f2bf(pd_emb[pd * PD + (tid - PD)]);
    }
}

// ============================================================
// K2: Ut[r][d] = sum_j bilin_W[d][j]*deprel_emb[r][j]  (f32)
//     v[d]    = sum_j bilin_W[d][j]*ext_rel[j]
// ============================================================
__global__ __launch_bounds__(256) void build_U(
    const float* __restrict__ bilin_W, const float* __restrict__ deprel_emb,
    const float* __restrict__ ext_rel, float* __restrict__ Ut, float* __restrict__ v)
{
    const int idx = blockIdx.x * 256 + threadIdx.x;
    if (idx < 64 * 1024) {
        const int r = idx >> 10, d = idx & 1023;
        float s = 0.f;
#pragma unroll
        for (int j = 0; j < RD; ++j) s += bilin_W[d * RD + j] * deprel_emb[r * RD + j];
        Ut[idx] = s;
    } else if (idx < 64 * 1024 + FD) {
        const int d = idx - 64 * 1024;
        float s = 0.f;
#pragma unroll
        for (int j = 0; j < RD; ++j) s += bilin_W[d * RD + j] * ext_rel[j];
        v[d] = s;
    }
}

// ============================================================
// K3a: Wt1[n][k] = fc1_W[k][n]  (bf16, [FD][NIN])
// ============================================================
__global__ __launch_bounds__(256) void build_Wt1(
    const float* __restrict__ W, ushort_t* __restrict__ Wt)
{
    const int idx = blockIdx.x * 256 + threadIdx.x;
    if (idx >= FD * NIN) return;
    const int n = idx / NIN, k = idx % NIN;
    Wt[idx] = f2bf(W[(size_t)k * FD + n]);
}

// ============================================================
// K3b: WcatT[c][k], c=t*128+f; taps t: 0-1 -> W_k2, 2-4 -> W_k3, 5-8 -> W_k4
// ============================================================
__global__ __launch_bounds__(256) void build_WcatT(
    const float* __restrict__ W2, const float* __restrict__ W3,
    const float* __restrict__ W4, ushort_t* __restrict__ Wt)
{
    const int idx = blockIdx.x * 256 + threadIdx.x;
    if (idx >= NCAT * FD) return;
    const int c = idx / FD;
    const int k = idx % FD;
    const int t = c >> 7, f = c & 127;
    float val;
    if (t < 2)      val = W2[((size_t)t * FD + k) * NF + f];
    else if (t < 5) val = W3[((size_t)(t - 2) * FD + k) * NF + f];
    else            val = W4[((size_t)(t - 5) * FD + k) * NF + f];
    Wt[idx] = f2bf(val);
}

// ============================================================
// K4/K7: MFMA bf16 GEMM  C[MxN] = act(A[MxK] @ Bt[NxK]^T + bias)  (C bf16)
// 128x128 tile, 256 threads = 4 waves (2x2), each wave 64x64 via 4x4
// mfma_f32_16x16x32_bf16 fragments. BK=32. global_load_lds width 16.
// ============================================================
template<int DO_RELU, int HAS_BIAS>
__global__ __launch_bounds__(256) void gemm_mfma_bt(
    const ushort_t* __restrict__ A,   // [M][K] bf16
    const ushort_t* __restrict__ Bt,  // [N][K] bf16
    const float* __restrict__ bias,   // [N] (f32) or null
    ushort_t* __restrict__ C,         // [M][N] bf16
    int M, int N, int K)
{
    __shared__ ushort_t As[128 * 32];
    __shared__ ushort_t Bs[128 * 32];
    const int tid = threadIdx.x;
    const int wid = tid >> 6, lane = tid & 63;
    const int wr = wid >> 1, wc = wid & 1;
    const int row0 = blockIdx.y * 128, col0 = blockIdx.x * 128;
    const int lr = lane & 15, lk = lane >> 4;

    f32x4 acc[4][4] = {};

    const ushort_t* gA = A + (size_t)row0 * K;
    const ushort_t* gB = Bt + (size_t)col0 * K;

    for (int k0 = 0; k0 < K; k0 += 32) {
#pragma unroll
        for (int i = 0; i < 2; ++i) {
            const int c = i * 256 + (wid << 6) + lane;  // chunk 0..511
            const int r = c >> 2;                        // tile row 0..127
            const int c8 = (c & 3) << 3;                 // k-offset 0/8/16/24
            __builtin_amdgcn_global_load_lds(
                (const __attribute__((address_space(1))) void*)(gA + (size_t)r * K + k0 + c8),
                (__attribute__((address_space(3))) void*)((char*)As + i * 4096 + (wid << 10)),
                16, 0, 0);
            __builtin_amdgcn_global_load_lds(
                (const __attribute__((address_space(1))) void*)(gB + (size_t)r * K + k0 + c8),
                (__attribute__((address_space(3))) void*)((char*)Bs + i * 4096 + (wid << 10)),
                16, 0, 0);
        }
        __syncthreads();
        bf16x8 af[4], bfr[4];
#pragma unroll
        for (int m = 0; m < 4; ++m)
            af[m] = *reinterpret_cast<const bf16x8*>(&As[(wr * 64 + m * 16 + lr) * 32 + lk * 8]);
#pragma unroll
        for (int n = 0; n < 4; ++n)
            bfr[n] = *reinterpret_cast<const bf16x8*>(&Bs[(wc * 64 + n * 16 + lr) * 32 + lk * 8]);
#pragma unroll
        for (int m = 0; m < 4; ++m)
#pragma unroll
            for (int n = 0; n < 4; ++n)
                acc[m][n] = __builtin_amdgcn_mfma_f32_16x16x32_bf16(af[m], bfr[n], acc[m][n], 0, 0, 0);
        __syncthreads();
    }
    // epilogue: C row = (lane>>4)*4 + reg, col = lane&15 within fragment
#pragma unroll
    for (int n = 0; n < 4; ++n) {
        const int col = col0 + wc * 64 + n * 16 + lr;
        const float bv = HAS_BIAS ? bias[col] : 0.f;
#pragma unroll
        for (int m = 0; m < 4; ++m) {
            const int rb = row0 + wr * 64 + m * 16 + lk * 4;
            const f32x4 v = acc[m][n];
#pragma unroll
            for (int j = 0; j < 4; ++j) {
                float x = v[j] + bv;
                if (DO_RELU) x = fmaxf(x, 0.f);
                C[(size_t)(rb + j) * N + col] = f2bf(x);
            }
        }
    }
}

// ============================================================
// K5: edge scores. One 64-lane wave per (b, n), n in [0, 2SL).
// node is bf16; lane handles 8 consecutive dims (d0 = lane*8).
// ============================================================
__global__ __launch_bounds__(256) void score_kernel(
    const ushort_t* __restrict__ node, const int* __restrict__ aspect_head,
    const int* __restrict__ deprel, const float* __restrict__ Ut,
    const float* __restrict__ v, const float* __restrict__ bilin_b,
    float* __restrict__ edge_score)
{
    const int g = blockIdx.x * 4 + (threadIdx.x >> 6);
    const int lane = threadIdx.x & 63;
    const int b = g >> 9;
    const int n = g & 511;
    const int d0 = lane * 8;
    typedef __attribute__((ext_vector_type(8))) unsigned short u16x8;
    float sum = 0.f;
    if (n < SL) {
        const int dr = deprel[b * SL + n];
        const int h = aspect_head[b * SL + n];
        const float* uc = Ut + (size_t)dr * 1024;
        const u16x8 nv = *reinterpret_cast<const u16x8*>(&node[((size_t)b * SL + n) * FD + d0]);
        if (h != 0) {
            const u16x8 dv = *reinterpret_cast<const u16x8*>(&node[((size_t)b * SL + (h - 1)) * FD + d0]);
#pragma unroll
            for (int i = 0; i < 8; ++i) sum += bf2f(dv[i]) * uc[d0 + i];
        }
#pragma unroll
        for (int i = 0; i < 8; ++i) sum += bf2f(nv[i]) * uc[FD + d0 + i];
    } else {
        const u16x8 nv = *reinterpret_cast<const u16x8*>(&node[((size_t)b * SL + (n - SL)) * FD + d0]);
#pragma unroll
        for (int i = 0; i < 8; ++i) sum += bf2f(nv[i]) * v[d0 + i];
    }
#pragma unroll
    for (int off = 32; off > 0; off >>= 1) sum += __shfl_xor(sum, off, 64);
    if (lane == 0) {
        const float sc = 1.f / (1.f + expf(-(sum + bilin_b[0])));
        edge_score[b * ES_STRIDE + 1 + n] = sc;
        if (n == 0) edge_score[b * ES_STRIDE] = 1.0f;
    }
}

// ============================================================
// K6: nw[b][s] = masked prod over path of edge_score; weight_norm[b] = sum_s
// ============================================================
__global__ __launch_bounds__(256) void nw_kernel(
    const float* __restrict__ edge_score, const int* __restrict__ path,
    const int* __restrict__ text_mask, const int* __restrict__ aspect_mask,
    float* __restrict__ nw, float* __restrict__ weight_norm)
{
    const int b = blockIdx.x, s = threadIdx.x;
    const float* es = edge_score + b * ES_STRIDE;
    const int* pp = path + ((size_t)b * SL + s) * PL;
    float p = 1.f;
#pragma unroll
    for (int l = 0; l < PL; ++l) p *= es[pp[l]];
    if (!(text_mask[b * SL + s] != 0 && aspect_mask[b * SL + s] == 0)) p = 0.f;
    nw[b * SL + s] = p;
    __shared__ float red[256];
    red[s] = p;
    __syncthreads();
    for (int off = 128; off > 0; off >>= 1) {
        if (s < off) red[s] += red[s + off];
        __syncthreads();
    }
    if (s == 0) weight_norm[b] = red[0];
}

// ============================================================
// K8: windowed scale + max-pool (Y bf16).  grid (BSZ, 3), 512 threads.
// ============================================================
__global__ __launch_bounds__(512) void pool_kernel(
    const ushort_t* __restrict__ Y, const float* __restrict__ nw,
    const float* __restrict__ b2, const float* __restrict__ b3,
    const float* __restrict__ b4, float* __restrict__ sentence)
{
    const int b = blockIdx.x;
    const int w = blockIdx.y;      // 0..2
    const int tid = threadIdx.x;   // 512
    const int q = tid >> 7;        // 0..3
    const int f = tid & 127;
    __shared__ float snw[SL];
    if (tid < SL) snw[tid] = nw[b * SL + tid];
    __syncthreads();
    const int kw = w + 2;
    const int tap0 = (w == 0) ? 0 : (w == 1) ? 2 : 5;
    const float* bias = (w == 0) ? b2 : (w == 1) ? b3 : b4;
    const float bf = bias[f];
    const int cn = SL - kw + 1;
    const float invk = 1.f / (float)kw;
    const ushort_t* Yb = Y + (size_t)b * SL * NCAT + (size_t)tap0 * NF + f;
    float mx = -INFINITY;
    for (int n = q; n < cn; n += 4) {
        float wsum = 0.f, acc = 0.f;
        for (int k = 0; k < kw; ++k) {
            wsum += snw[n + k];
            acc += bf2f(Yb[(size_t)(n + k) * NCAT + (size_t)k * NF]);
        }
        mx = fmaxf(mx, wsum * invk * acc + bf);
    }
    __shared__ float pm[4][NF];
    pm[q][f] = mx;
    __syncthreads();
    if (q == 0) {
        mx = fmaxf(fmaxf(pm[0][f], pm[1][f]), fmaxf(pm[2][f], pm[3][f]));
        sentence[(size_t)b * 384 + w * NF + f] = mx;
    }
}

// ============================================================
// K9: predicts = sentence @ fc_out_W + fc_out_b  -> out[0:96]
// ============================================================
__global__ __launch_bounds__(128) void fc_out_kernel(
    const float* __restrict__ sentence, const float* __restrict__ W,
    const float* __restrict__ bias, float* __restrict__ out)
{
    const int t = threadIdx.x;
    if (t >= BSZ * 3) return;
    const int b = t / 3, o = t % 3;
    float acc = bias[o];
    for (int i = 0; i < 384; ++i) acc = fmaf(sentence[b * 384 + i], W[i * 3 + o], acc);
    out[t] = acc;
}

// ============================================================
extern "C" void kernel_launch(void* const* d_in, const int* in_sizes, int n_in,
                              void* d_out, int out_size, void* d_ws, size_t ws_size,
                              hipStream_t stream)
{
    const float* bert      = (const float*)d_in[0];
    const int*   wgi       = (const int*)d_in[1];
    const int*   pos       = (const int*)d_in[2];
    const int*   deprel    = (const int*)d_in[3];
    const int*   path      = (const int*)d_in[4];
    const int*   ahead     = (const int*)d_in[5];
    const int*   tmask     = (const int*)d_in[6];
    const int*   amask     = (const int*)d_in[7];
    const float* pos_emb   = (const float*)d_in[8];
    const float* dre_emb   = (const float*)d_in[9];
    const float* pd_emb    = (const float*)d_in[10];
    const float* ext_rel   = (const float*)d_in[11];
    const float* fc1_W     = (const float*)d_in[12];
    const float* fc1_b     = (const float*)d_in[13];
    const float* bilin_W   = (const float*)d_in[14];
    const float* bilin_b   = (const float*)d_in[15];
    const float* W2        = (const float*)d_in[16];
    const float* b2        = (const float*)d_in[17];
    const float* W3        = (const float*)d_in[18];
    const float* b3        = (const float*)d_in[19];
    const float* W4        = (const float*)d_in[20];
    const float* b4        = (const float*)d_in[21];
    const float* fco_W     = (const float*)d_in[22];
    const float* fco_b     = (const float*)d_in[23];
    float* out = (float*)d_out;

    // ---- workspace layout (bytes) ----
    uint8_t* w = (uint8_t*)d_ws;
    // regionA: node_in bf16 (14.68MB) reused as Y bf16 (18.87MB)
    ushort_t* node_in = (ushort_t*)w;
    ushort_t* Y       = (ushort_t*)w;
    size_t off = (size_t)MROWS * NCAT * 2;            // 18,874,368
    ushort_t* node  = (ushort_t*)(w + off); off += (size_t)MROWS * FD * 2;   // 8.39MB
    ushort_t* Wt1   = (ushort_t*)(w + off); off += (size_t)FD * NIN * 2;     // 0.92MB
    ushort_t* WcatT = (ushort_t*)(w + off); off += (size_t)NCAT * FD * 2;    // 1.18MB
    float* Ut   = (float*)(w + off); off += (size_t)64 * 1024 * 4;
    float* vvec = (float*)(w + off); off += FD * 4;
    float* es   = (float*)(w + off); off += (size_t)BSZ * ES_STRIDE * 4;
    float* nw   = (float*)(w + off); off += (size_t)BSZ * SL * 4;
    float* sent = (float*)(w + off); off += (size_t)BSZ * 384 * 4;

    build_node_in<<<MROWS, 256, 0, stream>>>(bert, wgi, pos, path, pos_emb, pd_emb, node_in);
    build_U<<<258, 256, 0, stream>>>(bilin_W, dre_emb, ext_rel, Ut, vvec);
    build_Wt1<<<(FD * NIN + 255) / 256, 256, 0, stream>>>(fc1_W, Wt1);
    build_WcatT<<<(NCAT * FD + 255) / 256, 256, 0, stream>>>(W2, W3, W4, WcatT);

    // node = relu(node_in @ fc1_W + fc1_b)   [8192 x 512], K=896
    gemm_mfma_bt<1, 1><<<dim3(FD / 128, MROWS / 128), 256, 0, stream>>>(
        node_in, Wt1, fc1_b, node, MROWS, FD, NIN);

    score_kernel<<<(BSZ * 2 * SL) / 4, 256, 0, stream>>>(
        node, ahead, deprel, Ut, vvec, bilin_b, es);

    nw_kernel<<<BSZ, 256, 0, stream>>>(es, path, tmask, amask, nw, out + 96);

    // Y = node @ Wcat   [8192 x 1152], K=512  (overwrites node_in region)
    gemm_mfma_bt<0, 0><<<dim3(NCAT / 128, MROWS / 128), 256, 0, stream>>>(
        node, WcatT, nullptr, Y, MROWS, NCAT, FD);

    pool_kernel<<<dim3(BSZ, 3), 512, 0, stream>>>(Y, nw, b2, b3, b4, sent);

    fc_out_kernel<<<1, 128, 0, stream>>>(sent, fco_W, fco_b, out);
}

// Round 3
// 126.792 us; speedup vs baseline: 3.2212x; 1.3798x over previous
//
#include <hip/hip_runtime.h>
#include <hip/hip_bf16.h>
#include <math.h>

// ---- problem constants ----
#define BSZ 32
#define SL 256
#define WPL 4
#define NP 320
#define WD 768
#define PD 64
#define RD 64
#define FD 512
#define PL 8
#define NF 128
#define NIN 896          // WD + 2*PD
#define ES_STRIDE 513    // 2*SL + 1
#define NCAT 1152        // 9 taps * NF
#define MROWS (BSZ * SL) // 8192
#define NCH 8            // pool n-chunks

typedef __attribute__((ext_vector_type(8))) short bf16x8;
typedef __attribute__((ext_vector_type(4))) float f32x4;
typedef unsigned short ushort_t;

__device__ __forceinline__ ushort_t f2bf(float x) {
    __hip_bfloat16 h = __float2bfloat16(x);
    return *reinterpret_cast<ushort_t*>(&h);
}
__device__ __forceinline__ float bf2f(ushort_t u) {
    return __uint_as_float(((unsigned)u) << 16);
}

// ============================================================
// K1: node_in[bs][0:896] = [word(768) | pos_emb(64) | pathdepth_emb(64)]  (bf16)
// ============================================================
__global__ __launch_bounds__(256) void build_node_in(
    const float* __restrict__ bert, const int* __restrict__ wgi,
    const int* __restrict__ pos, const int* __restrict__ path,
    const float* __restrict__ pos_emb, const float* __restrict__ pd_emb,
    ushort_t* __restrict__ node_in)
{
    const int bs = blockIdx.x;     // 0..8191
    const int b = bs / SL;
    const int tid = threadIdx.x;
    const int* gi = wgi + (size_t)bs * WPL;
    const int i0 = gi[0], i1 = gi[1], i2 = gi[2], i3 = gi[3];
    const int npc = (i0 != 0) + (i1 != 0) + (i2 != 0) + (i3 != 0);
    const float inv = 1.0f / (float)(npc > 1 ? npc : 1);
    const float* r0 = bert + ((size_t)b * NP + (i0 - 1)) * WD;
    const float* r1 = bert + ((size_t)b * NP + (i1 - 1)) * WD;
    const float* r2 = bert + ((size_t)b * NP + (i2 - 1)) * WD;
    const float* r3 = bert + ((size_t)b * NP + (i3 - 1)) * WD;
    ushort_t* out = node_in + (size_t)bs * NIN;
    for (int c = tid; c < WD; c += 256) {
        float v = 0.f;
        if (i0) v += r0[c];
        if (i1) v += r1[c];
        if (i2) v += r2[c];
        if (i3) v += r3[c];
        out[c] = f2bf(v * inv);
    }
    if (tid < PD) {
        out[WD + tid] = f2bf(pos_emb[pos[bs] * PD + tid]);
    } else if (tid < 2 * PD) {
        const int* pp = path + (size_t)bs * PL;
        int pd = 0;
#pragma unroll
        for (int l = 0; l < PL; ++l) pd += (pp[l] != 0);
        out[WD + PD + (tid - PD)] = f2bf(pd_emb[pd * PD + (tid - PD)]);
    }
}

// ============================================================
// K2: Ut[r][d] = sum_j bilin_W[d][j]*deprel_emb[r][j]  (f32)
//     v[d]    = sum_j bilin_W[d][j]*ext_rel[j]
// ============================================================
__global__ __launch_bounds__(256) void build_U(
    const float* __restrict__ bilin_W, const float* __restrict__ deprel_emb,
    const float* __restrict__ ext_rel, float* __restrict__ Ut, float* __restrict__ v)
{
    const int idx = blockIdx.x * 256 + threadIdx.x;
    if (idx < 64 * 1024) {
        const int r = idx >> 10, d = idx & 1023;
        float s = 0.f;
#pragma unroll
        for (int j = 0; j < RD; ++j) s += bilin_W[d * RD + j] * deprel_emb[r * RD + j];
        Ut[idx] = s;
    } else if (idx < 64 * 1024 + FD) {
        const int d = idx - 64 * 1024;
        float s = 0.f;
#pragma unroll
        for (int j = 0; j < RD; ++j) s += bilin_W[d * RD + j] * ext_rel[j];
        v[d] = s;
    }
}

// ============================================================
// K3a: Wt1[n][k] = fc1_W[k][n]  (bf16, [FD][NIN])
// ============================================================
__global__ __launch_bounds__(256) void build_Wt1(
    const float* __restrict__ W, ushort_t* __restrict__ Wt)
{
    const int idx = blockIdx.x * 256 + threadIdx.x;
    if (idx >= FD * NIN) return;
    const int n = idx / NIN, k = idx % NIN;
    Wt[idx] = f2bf(W[(size_t)k * FD + n]);
}

// ============================================================
// K3b: WcatT[c][k], c=t*128+f; taps t: 0-1 -> W_k2, 2-4 -> W_k3, 5-8 -> W_k4
// ============================================================
__global__ __launch_bounds__(256) void build_WcatT(
    const float* __restrict__ W2, const float* __restrict__ W3,
    const float* __restrict__ W4, ushort_t* __restrict__ Wt)
{
    const int idx = blockIdx.x * 256 + threadIdx.x;
    if (idx >= NCAT * FD) return;
    const int c = idx / FD;
    const int k = idx % FD;
    const int t = c >> 7, f = c & 127;
    float val;
    if (t < 2)      val = W2[((size_t)t * FD + k) * NF + f];
    else if (t < 5) val = W3[((size_t)(t - 2) * FD + k) * NF + f];
    else            val = W4[((size_t)(t - 5) * FD + k) * NF + f];
    Wt[idx] = f2bf(val);
}

// ============================================================
// K4/K7: MFMA bf16 GEMM  C[MxN] = act(A[MxK] @ Bt[NxK]^T + bias)  (C bf16)
// 128x128 tile, 256 threads = 4 waves (2x2), each wave 64x64 via 4x4
// mfma_f32_16x16x32_bf16 fragments. BK=32. global_load_lds width 16.
// ============================================================
template<int DO_RELU, int HAS_BIAS>
__global__ __launch_bounds__(256) void gemm_mfma_bt(
    const ushort_t* __restrict__ A,   // [M][K] bf16
    const ushort_t* __restrict__ Bt,  // [N][K] bf16
    const float* __restrict__ bias,   // [N] (f32) or null
    ushort_t* __restrict__ C,         // [M][N] bf16
    int M, int N, int K)
{
    __shared__ ushort_t As[128 * 32];
    __shared__ ushort_t Bs[128 * 32];
    const int tid = threadIdx.x;
    const int wid = tid >> 6, lane = tid & 63;
    const int wr = wid >> 1, wc = wid & 1;
    const int row0 = blockIdx.y * 128, col0 = blockIdx.x * 128;
    const int lr = lane & 15, lk = lane >> 4;

    f32x4 acc[4][4] = {};

    const ushort_t* gA = A + (size_t)row0 * K;
    const ushort_t* gB = Bt + (size_t)col0 * K;

    for (int k0 = 0; k0 < K; k0 += 32) {
#pragma unroll
        for (int i = 0; i < 2; ++i) {
            const int c = i * 256 + (wid << 6) + lane;  // chunk 0..511
            const int r = c >> 2;                        // tile row 0..127
            const int c8 = (c & 3) << 3;                 // k-offset 0/8/16/24
            __builtin_amdgcn_global_load_lds(
                (const __attribute__((address_space(1))) void*)(gA + (size_t)r * K + k0 + c8),
                (__attribute__((address_space(3))) void*)((char*)As + i * 4096 + (wid << 10)),
                16, 0, 0);
            __builtin_amdgcn_global_load_lds(
                (const __attribute__((address_space(1))) void*)(gB + (size_t)r * K + k0 + c8),
                (__attribute__((address_space(3))) void*)((char*)Bs + i * 4096 + (wid << 10)),
                16, 0, 0);
        }
        __syncthreads();
        bf16x8 af[4], bfr[4];
#pragma unroll
        for (int m = 0; m < 4; ++m)
            af[m] = *reinterpret_cast<const bf16x8*>(&As[(wr * 64 + m * 16 + lr) * 32 + lk * 8]);
#pragma unroll
        for (int n = 0; n < 4; ++n)
            bfr[n] = *reinterpret_cast<const bf16x8*>(&Bs[(wc * 64 + n * 16 + lr) * 32 + lk * 8]);
#pragma unroll
        for (int m = 0; m < 4; ++m)
#pragma unroll
            for (int n = 0; n < 4; ++n)
                acc[m][n] = __builtin_amdgcn_mfma_f32_16x16x32_bf16(af[m], bfr[n], acc[m][n], 0, 0, 0);
        __syncthreads();
    }
    // epilogue: C row = (lane>>4)*4 + reg, col = lane&15 within fragment
#pragma unroll
    for (int n = 0; n < 4; ++n) {
        const int col = col0 + wc * 64 + n * 16 + lr;
        const float bv = HAS_BIAS ? bias[col] : 0.f;
#pragma unroll
        for (int m = 0; m < 4; ++m) {
            const int rb = row0 + wr * 64 + m * 16 + lk * 4;
            const f32x4 v = acc[m][n];
#pragma unroll
            for (int j = 0; j < 4; ++j) {
                float x = v[j] + bv;
                if (DO_RELU) x = fmaxf(x, 0.f);
                C[(size_t)(rb + j) * N + col] = f2bf(x);
            }
        }
    }
}

// ============================================================
// K5: edge scores. One 64-lane wave per (b, n), n in [0, 2SL).
// ============================================================
__global__ __launch_bounds__(256) void score_kernel(
    const ushort_t* __restrict__ node, const int* __restrict__ aspect_head,
    const int* __restrict__ deprel, const float* __restrict__ Ut,
    const float* __restrict__ v, const float* __restrict__ bilin_b,
    float* __restrict__ edge_score)
{
    const int g = blockIdx.x * 4 + (threadIdx.x >> 6);
    const int lane = threadIdx.x & 63;
    const int b = g >> 9;
    const int n = g & 511;
    const int d0 = lane * 8;
    typedef __attribute__((ext_vector_type(8))) unsigned short u16x8;
    float sum = 0.f;
    if (n < SL) {
        const int dr = deprel[b * SL + n];
        const int h = aspect_head[b * SL + n];
        const float* uc = Ut + (size_t)dr * 1024;
        const u16x8 nv = *reinterpret_cast<const u16x8*>(&node[((size_t)b * SL + n) * FD + d0]);
        if (h != 0) {
            const u16x8 dv = *reinterpret_cast<const u16x8*>(&node[((size_t)b * SL + (h - 1)) * FD + d0]);
#pragma unroll
            for (int i = 0; i < 8; ++i) sum += bf2f(dv[i]) * uc[d0 + i];
        }
#pragma unroll
        for (int i = 0; i < 8; ++i) sum += bf2f(nv[i]) * uc[FD + d0 + i];
    } else {
        const u16x8 nv = *reinterpret_cast<const u16x8*>(&node[((size_t)b * SL + (n - SL)) * FD + d0]);
#pragma unroll
        for (int i = 0; i < 8; ++i) sum += bf2f(nv[i]) * v[d0 + i];
    }
#pragma unroll
    for (int off = 32; off > 0; off >>= 1) sum += __shfl_xor(sum, off, 64);
    if (lane == 0) {
        const float sc = 1.f / (1.f + expf(-(sum + bilin_b[0])));
        edge_score[b * ES_STRIDE + 1 + n] = sc;
        if (n == 0) edge_score[b * ES_STRIDE] = 1.0f;
    }
}

// ============================================================
// K6: nw[b][s] = masked prod over path of edge_score; weight_norm[b] = sum_s
// ============================================================
__global__ __launch_bounds__(256) void nw_kernel(
    const float* __restrict__ edge_score, const int* __restrict__ path,
    const int* __restrict__ text_mask, const int* __restrict__ aspect_mask,
    float* __restrict__ nw, float* __restrict__ weight_norm)
{
    const int b = blockIdx.x, s = threadIdx.x;
    const float* es = edge_score + b * ES_STRIDE;
    const int* pp = path + ((size_t)b * SL + s) * PL;
    float p = 1.f;
#pragma unroll
    for (int l = 0; l < PL; ++l) p *= es[pp[l]];
    if (!(text_mask[b * SL + s] != 0 && aspect_mask[b * SL + s] == 0)) p = 0.f;
    nw[b * SL + s] = p;
    __shared__ float red[256];
    red[s] = p;
    __syncthreads();
    for (int off = 128; off > 0; off >>= 1) {
        if (s < off) red[s] += red[s + off];
        __syncthreads();
    }
    if (s == 0) weight_norm[b] = red[0];
}

// ============================================================
// K8: windowed scale + partial max-pool.  grid (BSZ, 3, NCH), 512 threads.
// Each block covers 32 output positions n in [ch*32, min(ch*32+32, cn)).
// Writes pmax[b][w][ch][f] (f32).
// ============================================================
__global__ __launch_bounds__(512) void pool_kernel(
    const ushort_t* __restrict__ Y, const float* __restrict__ nw,
    const float* __restrict__ b2, const float* __restrict__ b3,
    const float* __restrict__ b4, float* __restrict__ pmax)
{
    const int b = blockIdx.x;
    const int w = blockIdx.y;      // 0..2
    const int ch = blockIdx.z;     // 0..NCH-1
    const int tid = threadIdx.x;   // 512
    const int q = tid >> 7;        // 0..3
    const int f = tid & 127;
    const int kw = w + 2;
    const int tap0 = (w == 0) ? 0 : (w == 1) ? 2 : 5;
    const float* bias = (w == 0) ? b2 : (w == 1) ? b3 : b4;
    const float bf = bias[f];
    const int cn = SL - kw + 1;
    const int n0 = ch * 32;
    const int n1 = min(n0 + 32, cn);
    const float invk = 1.f / (float)kw;
    __shared__ float snw[40];      // rows n0 .. n0+32+kw-1
    if (tid < 40 && n0 + tid < SL) snw[tid] = nw[b * SL + n0 + tid];
    __syncthreads();
    const ushort_t* Yb = Y + (size_t)b * SL * NCAT + (size_t)tap0 * NF + f;
    float mx = -INFINITY;
    for (int n = n0 + q; n < n1; n += 4) {
        float wsum = 0.f, acc = 0.f;
        for (int k = 0; k < kw; ++k) {
            wsum += snw[n - n0 + k];
            acc += bf2f(Yb[(size_t)(n + k) * NCAT + (size_t)k * NF]);
        }
        mx = fmaxf(mx, wsum * invk * acc + bf);
    }
    __shared__ float pm[4][NF];
    pm[q][f] = mx;
    __syncthreads();
    if (q == 0) {
        mx = fmaxf(fmaxf(pm[0][f], pm[1][f]), fmaxf(pm[2][f], pm[3][f]));
        pmax[(((size_t)b * 3 + w) * NCH + ch) * NF + f] = mx;
    }
}

// ============================================================
// K9: finish: sentence[b][384] = max over ch of pmax, then
// predicts[b][3] = sentence . fc_out_W + fc_out_b  -> out[0:96]
// grid BSZ, 384 threads.
// ============================================================
__global__ __launch_bounds__(384) void finish_kernel(
    const float* __restrict__ pmax, const float* __restrict__ W,
    const float* __restrict__ bias, float* __restrict__ out)
{
    const int b = blockIdx.x;
    const int t = threadIdx.x;     // 0..383  (w*128+f)
    const float* src = pmax + ((size_t)b * 3 * NCH) * NF;
    // pmax[b][w][ch][f]; t = w*128+f -> base = w*NCH*NF + f
    const int w = t >> 7, f = t & 127;
    const float* p = src + (size_t)w * NCH * NF + f;
    float mx = -INFINITY;
#pragma unroll
    for (int ch = 0; ch < NCH; ++ch) mx = fmaxf(mx, p[(size_t)ch * NF]);
    __shared__ float sent[384];
    sent[t] = mx;
    __syncthreads();
    if (t < 3) {
        float acc = bias[t];
        for (int i = 0; i < 384; ++i) acc = fmaf(sent[i], W[i * 3 + t], acc);
        out[b * 3 + t] = acc;
    }
}

// ============================================================
extern "C" void kernel_launch(void* const* d_in, const int* in_sizes, int n_in,
                              void* d_out, int out_size, void* d_ws, size_t ws_size,
                              hipStream_t stream)
{
    const float* bert      = (const float*)d_in[0];
    const int*   wgi       = (const int*)d_in[1];
    const int*   pos       = (const int*)d_in[2];
    const int*   deprel    = (const int*)d_in[3];
    const int*   path      = (const int*)d_in[4];
    const int*   ahead     = (const int*)d_in[5];
    const int*   tmask     = (const int*)d_in[6];
    const int*   amask     = (const int*)d_in[7];
    const float* pos_emb   = (const float*)d_in[8];
    const float* dre_emb   = (const float*)d_in[9];
    const float* pd_emb    = (const float*)d_in[10];
    const float* ext_rel   = (const float*)d_in[11];
    const float* fc1_W     = (const float*)d_in[12];
    const float* fc1_b     = (const float*)d_in[13];
    const float* bilin_W   = (const float*)d_in[14];
    const float* bilin_b   = (const float*)d_in[15];
    const float* W2        = (const float*)d_in[16];
    const float* b2        = (const float*)d_in[17];
    const float* W3        = (const float*)d_in[18];
    const float* b3        = (const float*)d_in[19];
    const float* W4        = (const float*)d_in[20];
    const float* b4        = (const float*)d_in[21];
    const float* fco_W     = (const float*)d_in[22];
    const float* fco_b     = (const float*)d_in[23];
    float* out = (float*)d_out;

    // ---- workspace layout (bytes) ----
    uint8_t* w = (uint8_t*)d_ws;
    ushort_t* node_in = (ushort_t*)w;   // reused as Y
    ushort_t* Y       = (ushort_t*)w;
    size_t off = (size_t)MROWS * NCAT * 2;            // 18,874,368
    ushort_t* node  = (ushort_t*)(w + off); off += (size_t)MROWS * FD * 2;
    ushort_t* Wt1   = (ushort_t*)(w + off); off += (size_t)FD * NIN * 2;
    ushort_t* WcatT = (ushort_t*)(w + off); off += (size_t)NCAT * FD * 2;
    float* Ut   = (float*)(w + off); off += (size_t)64 * 1024 * 4;
    float* vvec = (float*)(w + off); off += FD * 4;
    float* es   = (float*)(w + off); off += (size_t)BSZ * ES_STRIDE * 4;
    float* nw   = (float*)(w + off); off += (size_t)BSZ * SL * 4;
    float* pmax = (float*)(w + off); off += (size_t)BSZ * 3 * NCH * NF * 4;

    build_node_in<<<MROWS, 256, 0, stream>>>(bert, wgi, pos, path, pos_emb, pd_emb, node_in);
    build_U<<<258, 256, 0, stream>>>(bilin_W, dre_emb, ext_rel, Ut, vvec);
    build_Wt1<<<(FD * NIN + 255) / 256, 256, 0, stream>>>(fc1_W, Wt1);
    build_WcatT<<<(NCAT * FD + 255) / 256, 256, 0, stream>>>(W2, W3, W4, WcatT);

    // node = relu(node_in @ fc1_W + fc1_b)   [8192 x 512], K=896
    gemm_mfma_bt<1, 1><<<dim3(FD / 128, MROWS / 128), 256, 0, stream>>>(
        node_in, Wt1, fc1_b, node, MROWS, FD, NIN);

    score_kernel<<<(BSZ * 2 * SL) / 4, 256, 0, stream>>>(
        node, ahead, deprel, Ut, vvec, bilin_b, es);

    nw_kernel<<<BSZ, 256, 0, stream>>>(es, path, tmask, amask, nw, out + 96);

    // Y = node @ Wcat   [8192 x 1152], K=512  (overwrites node_in region)
    gemm_mfma_bt<0, 0><<<dim3(NCAT / 128, MROWS / 128), 256, 0, stream>>>(
        node, WcatT, nullptr, Y, MROWS, NCAT, FD);

    pool_kernel<<<dim3(BSZ, 3, NCH), 512, 0, stream>>>(Y, nw, b2, b3, b4, pmax);

    finish_kernel<<<BSZ, 384, 0, stream>>>(pmax, fco_W, fco_b, out);
}

// Round 4
// 124.576 us; speedup vs baseline: 3.2785x; 1.0178x over previous
//
#include <hip/hip_runtime.h>
#include <hip/hip_bf16.h>
#include <math.h>

// ---- problem constants ----
#define BSZ 32
#define SL 256
#define WPL 4
#define NP 320
#define WD 768
#define PD 64
#define RD 64
#define FD 512
#define PL 8
#define NF 128
#define NIN 896          // WD + 2*PD
#define ES_STRIDE 513    // 2*SL + 1
#define MROWS (BSZ * SL) // 8192
#define NCH 8            // pool n-chunks
#define NZ 384           // 3 windows * NF
#define KZ 2048          // 4 * FD  (window-taps folded into K)

typedef __attribute__((ext_vector_type(8))) short bf16x8;
typedef __attribute__((ext_vector_type(4))) float f32x4;
typedef unsigned short ushort_t;
typedef __attribute__((ext_vector_type(4))) ushort_t u16x4;

__device__ __forceinline__ ushort_t f2bf(float x) {
    __hip_bfloat16 h = __float2bfloat16(x);
    return *reinterpret_cast<ushort_t*>(&h);
}
__device__ __forceinline__ float bf2f(ushort_t u) {
    return __uint_as_float(((unsigned)u) << 16);
}

// ============================================================
// K1: node_in[bs][0:896] = [word(768) | pos_emb(64) | pathdepth_emb(64)] (bf16)
// float4 gather loads; one block per word.
// ============================================================
__global__ __launch_bounds__(256) void build_node_in(
    const float* __restrict__ bert, const int* __restrict__ wgi,
    const int* __restrict__ pos, const int* __restrict__ path,
    const float* __restrict__ pos_emb, const float* __restrict__ pd_emb,
    ushort_t* __restrict__ node_in)
{
    const int bs = blockIdx.x;     // 0..8191
    const int b = bs >> 8;
    const int tid = threadIdx.x;
    const int* gi = wgi + (size_t)bs * WPL;
    const int i0 = gi[0], i1 = gi[1], i2 = gi[2], i3 = gi[3];
    const int npc = (i0 != 0) + (i1 != 0) + (i2 != 0) + (i3 != 0);
    const float inv = 1.0f / (float)(npc > 1 ? npc : 1);
    ushort_t* out = node_in + (size_t)bs * NIN;
    if (tid < 192) {
        const float4* r0 = (const float4*)(bert + ((size_t)b * NP + (i0 - 1)) * WD);
        const float4* r1 = (const float4*)(bert + ((size_t)b * NP + (i1 - 1)) * WD);
        const float4* r2 = (const float4*)(bert + ((size_t)b * NP + (i2 - 1)) * WD);
        const float4* r3 = (const float4*)(bert + ((size_t)b * NP + (i3 - 1)) * WD);
        float4 s = make_float4(0.f, 0.f, 0.f, 0.f);
        if (i0) { float4 v = r0[tid]; s.x += v.x; s.y += v.y; s.z += v.z; s.w += v.w; }
        if (i1) { float4 v = r1[tid]; s.x += v.x; s.y += v.y; s.z += v.z; s.w += v.w; }
        if (i2) { float4 v = r2[tid]; s.x += v.x; s.y += v.y; s.z += v.z; s.w += v.w; }
        if (i3) { float4 v = r3[tid]; s.x += v.x; s.y += v.y; s.z += v.z; s.w += v.w; }
        u16x4 o;
        o[0] = f2bf(s.x * inv); o[1] = f2bf(s.y * inv);
        o[2] = f2bf(s.z * inv); o[3] = f2bf(s.w * inv);
        *reinterpret_cast<u16x4*>(&out[tid * 4]) = o;
    } else {
        const int e = tid - 192;   // 0..63
        out[WD + e] = f2bf(pos_emb[pos[bs] * PD + e]);
        const int* pp = path + (size_t)bs * PL;
        int pd = 0;
#pragma unroll
        for (int l = 0; l < PL; ++l) pd += (pp[l] != 0);
        out[WD + PD + e] = f2bf(pd_emb[pd * PD + e]);
    }
}

// ============================================================
// K2 (fused prep):
//  part0: Ut[r][d] = sum_j bilin_W[d][j]*deprel_emb[r][j]   (64*1024)
//  part1: v[d]     = sum_j bilin_W[d][j]*ext_rel[j]         (512)
//  part2: Wt1[n][k] = fc1_W[k][n]  bf16                      (458752)
//  part3: WzT[c][kp] = (k<kw) ? W_w[k][d][f] : 0  bf16       (786432)
//         c = w*128+f, kp = k*512+d, kw = w+2
//  part4: node pad rows zero                                  (1536)
// ============================================================
#define P0 65536
#define P1 (P0 + 512)
#define P2 (P1 + FD * NIN)
#define P3 (P2 + NZ * KZ)
#define P4 (P3 + 3 * FD)
__global__ __launch_bounds__(256) void prep_kernel(
    const float* __restrict__ bilin_W, const float* __restrict__ deprel_emb,
    const float* __restrict__ ext_rel, const float* __restrict__ fc1_W,
    const float* __restrict__ W2, const float* __restrict__ W3,
    const float* __restrict__ W4,
    float* __restrict__ Ut, float* __restrict__ v,
    ushort_t* __restrict__ Wt1, ushort_t* __restrict__ WzT,
    ushort_t* __restrict__ node)
{
    const int idx = blockIdx.x * 256 + threadIdx.x;
    if (idx < P0) {
        const int r = idx >> 10, d = idx & 1023;
        float s = 0.f;
#pragma unroll
        for (int j = 0; j < RD; ++j) s += bilin_W[d * RD + j] * deprel_emb[r * RD + j];
        Ut[idx] = s;
    } else if (idx < P1) {
        const int d = idx - P0;
        float s = 0.f;
#pragma unroll
        for (int j = 0; j < RD; ++j) s += bilin_W[d * RD + j] * ext_rel[j];
        v[d] = s;
    } else if (idx < P2) {
        const int j = idx - P1;
        const int k = j >> 9, n = j & 511;       // read coalesced over n
        Wt1[(size_t)n * NIN + k] = f2bf(fc1_W[(size_t)k * FD + n]);
    } else if (idx < P3) {
        const int j = idx - P2;
        const int kp = j / NZ, c = j - kp * NZ;  // read coalesced over c (f)
        const int w = c >> 7, f = c & 127;
        const int k = kp >> 9, d = kp & 511;
        const int kw = w + 2;
        float val = 0.f;
        if (k < kw) {
            const float* Wsrc = (w == 0) ? W2 : (w == 1) ? W3 : W4;
            val = Wsrc[((size_t)k * FD + d) * NF + f];
        }
        WzT[(size_t)c * KZ + kp] = f2bf(val);
    } else if (idx < P4) {
        const int j = idx - P3;
        node[(size_t)MROWS * FD + j] = 0;        // 3 zero pad rows
    }
}

// ============================================================
// K3: MFMA bf16 GEMM  C = relu(A[MxK] @ Bt[NxK]^T + bias)  (C bf16)
// 128x128 tile, 4 waves (2x2), 4x4 x mfma_f32_16x16x32_bf16, BK=32,
// global_load_lds width 16.  (node = relu(node_in @ fc1_W + b))
// ============================================================
__global__ __launch_bounds__(256) void gemm_node(
    const ushort_t* __restrict__ A,   // [M][NIN]
    const ushort_t* __restrict__ Bt,  // [FD][NIN]
    const float* __restrict__ bias,
    ushort_t* __restrict__ C)         // [M][FD]
{
    __shared__ ushort_t As[128 * 32];
    __shared__ ushort_t Bs[128 * 32];
    const int tid = threadIdx.x;
    const int wid = tid >> 6, lane = tid & 63;
    const int wr = wid >> 1, wc = wid & 1;
    const int row0 = blockIdx.y * 128, col0 = blockIdx.x * 128;
    const int lr = lane & 15, lk = lane >> 4;
    f32x4 acc[4][4] = {};
    const ushort_t* gA = A + (size_t)row0 * NIN;
    const ushort_t* gB = Bt + (size_t)col0 * NIN;
    for (int k0 = 0; k0 < NIN; k0 += 32) {
#pragma unroll
        for (int i = 0; i < 2; ++i) {
            const int c = i * 256 + (wid << 6) + lane;
            const int r = c >> 2;
            const int c8 = (c & 3) << 3;
            __builtin_amdgcn_global_load_lds(
                (const __attribute__((address_space(1))) void*)(gA + (size_t)r * NIN + k0 + c8),
                (__attribute__((address_space(3))) void*)((char*)As + i * 4096 + (wid << 10)),
                16, 0, 0);
            __builtin_amdgcn_global_load_lds(
                (const __attribute__((address_space(1))) void*)(gB + (size_t)r * NIN + k0 + c8),
                (__attribute__((address_space(3))) void*)((char*)Bs + i * 4096 + (wid << 10)),
                16, 0, 0);
        }
        __syncthreads();
        bf16x8 af[4], bfr[4];
#pragma unroll
        for (int m = 0; m < 4; ++m)
            af[m] = *reinterpret_cast<const bf16x8*>(&As[(wr * 64 + m * 16 + lr) * 32 + lk * 8]);
#pragma unroll
        for (int n = 0; n < 4; ++n)
            bfr[n] = *reinterpret_cast<const bf16x8*>(&Bs[(wc * 64 + n * 16 + lr) * 32 + lk * 8]);
#pragma unroll
        for (int m = 0; m < 4; ++m)
#pragma unroll
            for (int n = 0; n < 4; ++n)
                acc[m][n] = __builtin_amdgcn_mfma_f32_16x16x32_bf16(af[m], bfr[n], acc[m][n], 0, 0, 0);
        __syncthreads();
    }
#pragma unroll
    for (int n = 0; n < 4; ++n) {
        const int col = col0 + wc * 64 + n * 16 + lr;
        const float bv = bias[col];
#pragma unroll
        for (int m = 0; m < 4; ++m) {
            const int rb = row0 + wr * 64 + m * 16 + lk * 4;
            const f32x4 vv = acc[m][n];
#pragma unroll
            for (int j = 0; j < 4; ++j)
                C[(size_t)(rb + j) * FD + col] = f2bf(fmaxf(vv[j] + bv, 0.f));
        }
    }
}

// ============================================================
// K6: GEMM-Z — windowed conv as GEMM over K'=2048.
// Z[m][c] = sum_{kp} node[m + (kp>>9)][kp&511] * WzT[c][kp]
// A-tile staging = node tile with row offset koff = kp>>9.
// grid (NZ/128=3, MROWS/128=64)
// ============================================================
__global__ __launch_bounds__(256) void gemm_z(
    const ushort_t* __restrict__ node,  // [(MROWS+3)][FD]
    const ushort_t* __restrict__ WzT,   // [NZ][KZ]
    ushort_t* __restrict__ Z)           // [MROWS][NZ]
{
    __shared__ ushort_t As[128 * 32];
    __shared__ ushort_t Bs[128 * 32];
    const int tid = threadIdx.x;
    const int wid = tid >> 6, lane = tid & 63;
    const int wr = wid >> 1, wc = wid & 1;
    const int row0 = blockIdx.y * 128, col0 = blockIdx.x * 128;
    const int lr = lane & 15, lk = lane >> 4;
    f32x4 acc[4][4] = {};
    const ushort_t* gB = WzT + (size_t)col0 * KZ;
    for (int k0 = 0; k0 < KZ; k0 += 32) {
        const int koff = k0 >> 9;        // node row offset 0..3
        const int d0 = k0 & 511;
        const ushort_t* gA = node + (size_t)(row0 + koff) * FD + d0;
#pragma unroll
        for (int i = 0; i < 2; ++i) {
            const int c = i * 256 + (wid << 6) + lane;
            const int r = c >> 2;
            const int c8 = (c & 3) << 3;
            __builtin_amdgcn_global_load_lds(
                (const __attribute__((address_space(1))) void*)(gA + (size_t)r * FD + c8),
                (__attribute__((address_space(3))) void*)((char*)As + i * 4096 + (wid << 10)),
                16, 0, 0);
            __builtin_amdgcn_global_load_lds(
                (const __attribute__((address_space(1))) void*)(gB + (size_t)r * KZ + k0 + c8),
                (__attribute__((address_space(3))) void*)((char*)Bs + i * 4096 + (wid << 10)),
                16, 0, 0);
        }
        __syncthreads();
        bf16x8 af[4], bfr[4];
#pragma unroll
        for (int m = 0; m < 4; ++m)
            af[m] = *reinterpret_cast<const bf16x8*>(&As[(wr * 64 + m * 16 + lr) * 32 + lk * 8]);
#pragma unroll
        for (int n = 0; n < 4; ++n)
            bfr[n] = *reinterpret_cast<const bf16x8*>(&Bs[(wc * 64 + n * 16 + lr) * 32 + lk * 8]);
#pragma unroll
        for (int m = 0; m < 4; ++m)
#pragma unroll
            for (int n = 0; n < 4; ++n)
                acc[m][n] = __builtin_amdgcn_mfma_f32_16x16x32_bf16(af[m], bfr[n], acc[m][n], 0, 0, 0);
        __syncthreads();
    }
#pragma unroll
    for (int n = 0; n < 4; ++n) {
        const int col = col0 + wc * 64 + n * 16 + lr;
#pragma unroll
        for (int m = 0; m < 4; ++m) {
            const int rb = row0 + wr * 64 + m * 16 + lk * 4;
            const f32x4 vv = acc[m][n];
#pragma unroll
            for (int j = 0; j < 4; ++j)
                Z[(size_t)(rb + j) * NZ + col] = f2bf(vv[j]);
        }
    }
}

// ============================================================
// K4: edge scores. One 64-lane wave per (b, n), n in [0, 2SL).
// ============================================================
__global__ __launch_bounds__(256) void score_kernel(
    const ushort_t* __restrict__ node, const int* __restrict__ aspect_head,
    const int* __restrict__ deprel, const float* __restrict__ Ut,
    const float* __restrict__ v, const float* __restrict__ bilin_b,
    float* __restrict__ edge_score)
{
    const int g = blockIdx.x * 4 + (threadIdx.x >> 6);
    const int lane = threadIdx.x & 63;
    const int b = g >> 9;
    const int n = g & 511;
    const int d0 = lane * 8;
    typedef __attribute__((ext_vector_type(8))) unsigned short u16x8;
    float sum = 0.f;
    if (n < SL) {
        const int dr = deprel[b * SL + n];
        const int h = aspect_head[b * SL + n];
        const float* uc = Ut + (size_t)dr * 1024;
        const u16x8 nv = *reinterpret_cast<const u16x8*>(&node[((size_t)b * SL + n) * FD + d0]);
        if (h != 0) {
            const u16x8 dv = *reinterpret_cast<const u16x8*>(&node[((size_t)b * SL + (h - 1)) * FD + d0]);
#pragma unroll
            for (int i = 0; i < 8; ++i) sum += bf2f(dv[i]) * uc[d0 + i];
        }
#pragma unroll
        for (int i = 0; i < 8; ++i) sum += bf2f(nv[i]) * uc[FD + d0 + i];
    } else {
        const u16x8 nv = *reinterpret_cast<const u16x8*>(&node[((size_t)b * SL + (n - SL)) * FD + d0]);
#pragma unroll
        for (int i = 0; i < 8; ++i) sum += bf2f(nv[i]) * v[d0 + i];
    }
#pragma unroll
    for (int off = 32; off > 0; off >>= 1) sum += __shfl_xor(sum, off, 64);
    if (lane == 0) {
        const float sc = 1.f / (1.f + expf(-(sum + bilin_b[0])));
        edge_score[b * ES_STRIDE + 1 + n] = sc;
        if (n == 0) edge_score[b * ES_STRIDE] = 1.0f;
    }
}

// ============================================================
// K5: nw[b][s] = masked prod over path of edge_score; weight_norm[b] = sum_s
// ============================================================
__global__ __launch_bounds__(256) void nw_kernel(
    const float* __restrict__ edge_score, const int* __restrict__ path,
    const int* __restrict__ text_mask, const int* __restrict__ aspect_mask,
    float* __restrict__ nw, float* __restrict__ weight_norm)
{
    const int b = blockIdx.x, s = threadIdx.x;
    const float* es = edge_score + b * ES_STRIDE;
    const int* pp = path + ((size_t)b * SL + s) * PL;
    float p = 1.f;
#pragma unroll
    for (int l = 0; l < PL; ++l) p *= es[pp[l]];
    if (!(text_mask[b * SL + s] != 0 && aspect_mask[b * SL + s] == 0)) p = 0.f;
    nw[b * SL + s] = p;
    __shared__ float red[256];
    red[s] = p;
    __syncthreads();
    for (int off = 128; off > 0; off >>= 1) {
        if (s < off) red[s] += red[s + off];
        __syncthreads();
    }
    if (s == 0) weight_norm[b] = red[0];
}

// ============================================================
// K7: pool over Z.  grid (BSZ, 3, NCH), 512 threads.
// pmax[b][w][ch][f] = max_{n in chunk} mean(nw[n..n+kw-1]) * Z[b*SL+n][w*128+f] + bias[f]
// ============================================================
__global__ __launch_bounds__(512) void pool_kernel(
    const ushort_t* __restrict__ Z, const float* __restrict__ nw,
    const float* __restrict__ b2, const float* __restrict__ b3,
    const float* __restrict__ b4, float* __restrict__ pmax)
{
    const int b = blockIdx.x;
    const int w = blockIdx.y;      // 0..2
    const int ch = blockIdx.z;     // 0..NCH-1
    const int tid = threadIdx.x;   // 512
    const int q = tid >> 7;        // 0..3
    const int f = tid & 127;
    const int kw = w + 2;
    const float* bias = (w == 0) ? b2 : (w == 1) ? b3 : b4;
    const float bf = bias[f];
    const int cn = SL - kw + 1;
    const int n0 = ch * 32;
    const int n1 = min(n0 + 32, cn);
    const float invk = 1.f / (float)kw;
    __shared__ float snw[40];
    if (tid < 40 && n0 + tid < SL) snw[tid] = nw[b * SL + n0 + tid];
    __syncthreads();
    const ushort_t* Zb = Z + ((size_t)b * SL) * NZ + (size_t)w * NF + f;
    float mx = -INFINITY;
    for (int n = n0 + q; n < n1; n += 4) {
        float wsum = 0.f;
#pragma unroll
        for (int k = 0; k < 4; ++k) wsum += (k < kw) ? snw[n - n0 + k] : 0.f;
        mx = fmaxf(mx, wsum * invk * bf2f(Zb[(size_t)n * NZ]) + bf);
    }
    __shared__ float pm[4][NF];
    pm[q][f] = mx;
    __syncthreads();
    if (q == 0) {
        mx = fmaxf(fmaxf(pm[0][f], pm[1][f]), fmaxf(pm[2][f], pm[3][f]));
        pmax[(((size_t)b * 3 + w) * NCH + ch) * NF + f] = mx;
    }
}

// ============================================================
// K8: finish: sentence = max over ch; predicts = sentence @ fc_out_W + b
// ============================================================
__global__ __launch_bounds__(384) void finish_kernel(
    const float* __restrict__ pmax, const float* __restrict__ W,
    const float* __restrict__ bias, float* __restrict__ out)
{
    const int b = blockIdx.x;
    const int t = threadIdx.x;     // 0..383
    const int w = t >> 7, f = t & 127;
    const float* p = pmax + ((size_t)b * 3 + w) * NCH * NF + f;
    float mx = -INFINITY;
#pragma unroll
    for (int ch = 0; ch < NCH; ++ch) mx = fmaxf(mx, p[(size_t)ch * NF]);
    __shared__ float sent[384];
    sent[t] = mx;
    __syncthreads();
    if (t < 3) {
        float acc = bias[t];
        for (int i = 0; i < 384; ++i) acc = fmaf(sent[i], W[i * 3 + t], acc);
        out[b * 3 + t] = acc;
    }
}

// ============================================================
extern "C" void kernel_launch(void* const* d_in, const int* in_sizes, int n_in,
                              void* d_out, int out_size, void* d_ws, size_t ws_size,
                              hipStream_t stream)
{
    const float* bert      = (const float*)d_in[0];
    const int*   wgi       = (const int*)d_in[1];
    const int*   pos       = (const int*)d_in[2];
    const int*   deprel    = (const int*)d_in[3];
    const int*   path      = (const int*)d_in[4];
    const int*   ahead     = (const int*)d_in[5];
    const int*   tmask     = (const int*)d_in[6];
    const int*   amask     = (const int*)d_in[7];
    const float* pos_emb   = (const float*)d_in[8];
    const float* dre_emb   = (const float*)d_in[9];
    const float* pd_emb    = (const float*)d_in[10];
    const float* ext_rel   = (const float*)d_in[11];
    const float* fc1_W     = (const float*)d_in[12];
    const float* fc1_b     = (const float*)d_in[13];
    const float* bilin_W   = (const float*)d_in[14];
    const float* bilin_b   = (const float*)d_in[15];
    const float* W2        = (const float*)d_in[16];
    const float* b2        = (const float*)d_in[17];
    const float* W3        = (const float*)d_in[18];
    const float* b3        = (const float*)d_in[19];
    const float* W4        = (const float*)d_in[20];
    const float* b4        = (const float*)d_in[21];
    const float* fco_W     = (const float*)d_in[22];
    const float* fco_b     = (const float*)d_in[23];
    float* out = (float*)d_out;

    // ---- workspace layout ----
    uint8_t* w = (uint8_t*)d_ws;
    ushort_t* node_in = (ushort_t*)w;                 // 14.68 MB, reused as Z (6.29 MB)
    ushort_t* Z       = (ushort_t*)w;
    size_t off = (size_t)MROWS * NIN * 2;
    ushort_t* node = (ushort_t*)(w + off); off += (size_t)(MROWS + 3) * FD * 2;
    ushort_t* Wt1  = (ushort_t*)(w + off); off += (size_t)FD * NIN * 2;
    ushort_t* WzT  = (ushort_t*)(w + off); off += (size_t)NZ * KZ * 2;
    float* Ut   = (float*)(w + off); off += (size_t)64 * 1024 * 4;
    float* vvec = (float*)(w + off); off += FD * 4;
    float* es   = (float*)(w + off); off += (size_t)BSZ * ES_STRIDE * 4;
    float* nw   = (float*)(w + off); off += (size_t)BSZ * SL * 4;
    float* pmax = (float*)(w + off); off += (size_t)BSZ * 3 * NCH * NF * 4;

    build_node_in<<<MROWS, 256, 0, stream>>>(bert, wgi, pos, path, pos_emb, pd_emb, node_in);
    prep_kernel<<<P4 / 256, 256, 0, stream>>>(bilin_W, dre_emb, ext_rel, fc1_W,
                                              W2, W3, W4, Ut, vvec, Wt1, WzT, node);

    gemm_node<<<dim3(FD / 128, MROWS / 128), 256, 0, stream>>>(node_in, Wt1, fc1_b, node);

    score_kernel<<<(BSZ * 2 * SL) / 4, 256, 0, stream>>>(
        node, ahead, deprel, Ut, vvec, bilin_b, es);

    nw_kernel<<<BSZ, 256, 0, stream>>>(es, path, tmask, amask, nw, out + 96);

    gemm_z<<<dim3(NZ / 128, MROWS / 128), 256, 0, stream>>>(node, WzT, Z);

    pool_kernel<<<dim3(BSZ, 3, NCH), 512, 0, stream>>>(Z, nw, b2, b3, b4, pmax);

    finish_kernel<<<BSZ, 384, 0, stream>>>(pmax, fco_W, fco_b, out);
}

// Round 5
// 116.223 us; speedup vs baseline: 3.5141x; 1.0719x over previous
//
#include <hip/hip_runtime.h>
#include <hip/hip_bf16.h>
#include <math.h>

// ---- problem constants ----
#define BSZ 32
#define SL 256
#define WPL 4
#define NP 320
#define WD 768
#define PD 64
#define RD 64
#define FD 512
#define PL 8
#define NF 128
#define NIN 896          // WD + 2*PD
#define ES_STRIDE 513    // 2*SL + 1
#define MROWS (BSZ * SL) // 8192
#define NZ 384           // 3 windows * NF
#define KZ 2048          // 4 * FD  (window-taps folded into K)

typedef __attribute__((ext_vector_type(8))) short bf16x8;
typedef __attribute__((ext_vector_type(4))) float f32x4;
typedef unsigned short ushort_t;
typedef __attribute__((ext_vector_type(4))) ushort_t u16x4;

__device__ __forceinline__ ushort_t f2bf(float x) {
    __hip_bfloat16 h = __float2bfloat16(x);
    return *reinterpret_cast<ushort_t*>(&h);
}
__device__ __forceinline__ float bf2f(ushort_t u) {
    return __uint_as_float(((unsigned)u) << 16);
}

// ============================================================
// K1: node_in[bs][0:896] = [word(768) | pos_emb(64) | pathdepth_emb(64)] (bf16)
// ============================================================
__global__ __launch_bounds__(256) void build_node_in(
    const float* __restrict__ bert, const int* __restrict__ wgi,
    const int* __restrict__ pos, const int* __restrict__ path,
    const float* __restrict__ pos_emb, const float* __restrict__ pd_emb,
    ushort_t* __restrict__ node_in)
{
    const int bs = blockIdx.x;     // 0..8191
    const int b = bs >> 8;
    const int tid = threadIdx.x;
    const int* gi = wgi + (size_t)bs * WPL;
    const int i0 = gi[0], i1 = gi[1], i2 = gi[2], i3 = gi[3];
    const int npc = (i0 != 0) + (i1 != 0) + (i2 != 0) + (i3 != 0);
    const float inv = 1.0f / (float)(npc > 1 ? npc : 1);
    ushort_t* out = node_in + (size_t)bs * NIN;
    if (tid < 192) {
        const float4* r0 = (const float4*)(bert + ((size_t)b * NP + (i0 - 1)) * WD);
        const float4* r1 = (const float4*)(bert + ((size_t)b * NP + (i1 - 1)) * WD);
        const float4* r2 = (const float4*)(bert + ((size_t)b * NP + (i2 - 1)) * WD);
        const float4* r3 = (const float4*)(bert + ((size_t)b * NP + (i3 - 1)) * WD);
        float4 s = make_float4(0.f, 0.f, 0.f, 0.f);
        if (i0) { float4 v = r0[tid]; s.x += v.x; s.y += v.y; s.z += v.z; s.w += v.w; }
        if (i1) { float4 v = r1[tid]; s.x += v.x; s.y += v.y; s.z += v.z; s.w += v.w; }
        if (i2) { float4 v = r2[tid]; s.x += v.x; s.y += v.y; s.z += v.z; s.w += v.w; }
        if (i3) { float4 v = r3[tid]; s.x += v.x; s.y += v.y; s.z += v.z; s.w += v.w; }
        u16x4 o;
        o[0] = f2bf(s.x * inv); o[1] = f2bf(s.y * inv);
        o[2] = f2bf(s.z * inv); o[3] = f2bf(s.w * inv);
        *reinterpret_cast<u16x4*>(&out[tid * 4]) = o;
    } else {
        const int e = tid - 192;   // 0..63
        out[WD + e] = f2bf(pos_emb[pos[bs] * PD + e]);
        const int* pp = path + (size_t)bs * PL;
        int pd = 0;
#pragma unroll
        for (int l = 0; l < PL; ++l) pd += (pp[l] != 0);
        out[WD + PD + e] = f2bf(pd_emb[pd * PD + e]);
    }
}

// ============================================================
// K2 (fused prep): Ut, v, Wt1 (fc1_W^T bf16), WzT, node pad rows
// ============================================================
#define P0 65536
#define P1 (P0 + 512)
#define P2 (P1 + FD * NIN)
#define P3 (P2 + NZ * KZ)
#define P4 (P3 + 3 * FD)
__global__ __launch_bounds__(256) void prep_kernel(
    const float* __restrict__ bilin_W, const float* __restrict__ deprel_emb,
    const float* __restrict__ ext_rel, const float* __restrict__ fc1_W,
    const float* __restrict__ W2, const float* __restrict__ W3,
    const float* __restrict__ W4,
    float* __restrict__ Ut, float* __restrict__ v,
    ushort_t* __restrict__ Wt1, ushort_t* __restrict__ WzT,
    ushort_t* __restrict__ node)
{
    const int idx = blockIdx.x * 256 + threadIdx.x;
    if (idx < P0) {
        const int r = idx >> 10, d = idx & 1023;
        float s = 0.f;
#pragma unroll
        for (int j = 0; j < RD; ++j) s += bilin_W[d * RD + j] * deprel_emb[r * RD + j];
        Ut[idx] = s;
    } else if (idx < P1) {
        const int d = idx - P0;
        float s = 0.f;
#pragma unroll
        for (int j = 0; j < RD; ++j) s += bilin_W[d * RD + j] * ext_rel[j];
        v[d] = s;
    } else if (idx < P2) {
        const int j = idx - P1;
        const int k = j >> 9, n = j & 511;       // read coalesced over n
        Wt1[(size_t)n * NIN + k] = f2bf(fc1_W[(size_t)k * FD + n]);
    } else if (idx < P3) {
        const int j = idx - P2;
        const int kp = j / NZ, c = j - kp * NZ;  // read coalesced over c (f)
        const int w = c >> 7, f = c & 127;
        const int k = kp >> 9, d = kp & 511;
        const int kw = w + 2;
        float val = 0.f;
        if (k < kw) {
            const float* Wsrc = (w == 0) ? W2 : (w == 1) ? W3 : W4;
            val = Wsrc[((size_t)k * FD + d) * NF + f];
        }
        WzT[(size_t)c * KZ + kp] = f2bf(val);
    } else if (idx < P4) {
        const int j = idx - P3;
        node[(size_t)MROWS * FD + j] = 0;        // 3 zero pad rows
    }
}

// ============================================================
// K3: node = relu(node_in @ fc1_W + b).  BM=128 x BN=64 tile, 4 waves 2x2,
// wave = 64x32 (4x2 frags of 16x16x32).  Swizzled staging (src-side XOR),
// swizzled ds_read -> 2-way conflicts only.  grid (8, 64) = 512 blocks.
// ============================================================
__global__ __launch_bounds__(256) void gemm_node(
    const ushort_t* __restrict__ A,   // [M][NIN]
    const ushort_t* __restrict__ Bt,  // [FD][NIN]
    const float* __restrict__ bias,
    ushort_t* __restrict__ C)         // [M][FD]
{
    __shared__ ushort_t As[128 * 32];
    __shared__ ushort_t Bs[64 * 32];
    const int tid = threadIdx.x;
    const int wid = tid >> 6, lane = tid & 63;
    const int wr = wid >> 1, wc = wid & 1;
    const int row0 = blockIdx.y * 128, col0 = blockIdx.x * 64;
    const int lr = lane & 15, lk = lane >> 4;
    f32x4 acc[4][2] = {};
    const ushort_t* gA0 = A + (size_t)row0 * NIN;
    const ushort_t* gB0 = Bt + (size_t)col0 * NIN;
    for (int k0 = 0; k0 < NIN; k0 += 32) {
#pragma unroll
        for (int i = 0; i < 2; ++i) {
            const int c = i * 256 + tid;
            const int r = c >> 2, q = c & 3;
            const int qs = q ^ ((r >> 1) & 3);
            __builtin_amdgcn_global_load_lds(
                (const __attribute__((address_space(1))) void*)(gA0 + (size_t)r * NIN + k0 + qs * 8),
                (__attribute__((address_space(3))) void*)((char*)As + i * 4096 + (wid << 10)),
                16, 0, 0);
        }
        {
            const int r = tid >> 2, q = tid & 3;
            const int qs = q ^ ((r >> 1) & 3);
            __builtin_amdgcn_global_load_lds(
                (const __attribute__((address_space(1))) void*)(gB0 + (size_t)r * NIN + k0 + qs * 8),
                (__attribute__((address_space(3))) void*)((char*)Bs + (wid << 10)),
                16, 0, 0);
        }
        __syncthreads();
        bf16x8 af[4], bfr[2];
#pragma unroll
        for (int m = 0; m < 4; ++m) {
            const int fr = wr * 64 + m * 16 + lr;
            af[m] = *reinterpret_cast<const bf16x8*>(&As[fr * 32 + ((lk ^ ((fr >> 1) & 3)) << 3)]);
        }
#pragma unroll
        for (int n = 0; n < 2; ++n) {
            const int fr = wc * 32 + n * 16 + lr;
            bfr[n] = *reinterpret_cast<const bf16x8*>(&Bs[fr * 32 + ((lk ^ ((fr >> 1) & 3)) << 3)]);
        }
#pragma unroll
        for (int m = 0; m < 4; ++m)
#pragma unroll
            for (int n = 0; n < 2; ++n)
                acc[m][n] = __builtin_amdgcn_mfma_f32_16x16x32_bf16(af[m], bfr[n], acc[m][n], 0, 0, 0);
        __syncthreads();
    }
#pragma unroll
    for (int n = 0; n < 2; ++n) {
        const int col = col0 + wc * 32 + n * 16 + lr;
        const float bv = bias[col];
#pragma unroll
        for (int m = 0; m < 4; ++m) {
            const int rb = row0 + wr * 64 + m * 16 + lk * 4;
            const f32x4 vv = acc[m][n];
#pragma unroll
            for (int j = 0; j < 4; ++j)
                C[(size_t)(rb + j) * FD + col] = f2bf(fmaxf(vv[j] + bv, 0.f));
        }
    }
}

// ============================================================
// K6: GEMM-Z + fused windowed-scale + max-pool.
// BM=64 x BN=64, 4 waves 2x2, wave = 32x32 (2x2 frags). K=2048 with
// A-row shift per 512-chunk.  grid (6, 128) = 768 blocks.
// Epilogue: val = mean(nw[n..n+kw-1]) * acc + bias[f]; per-(wave,col) max
// -> pmaxp[(by*2+wr)][col]  (f32 [256][384]).
// ============================================================
__global__ __launch_bounds__(256) void gemm_z_pool(
    const ushort_t* __restrict__ node,  // [(MROWS+3)][FD]
    const ushort_t* __restrict__ WzT,   // [NZ][KZ]
    const float* __restrict__ nw,
    const float* __restrict__ b2, const float* __restrict__ b3,
    const float* __restrict__ b4,
    float* __restrict__ pmaxp)          // [256][NZ]
{
    __shared__ ushort_t As[64 * 32];
    __shared__ ushort_t Bs[64 * 32];
    const int tid = threadIdx.x;
    const int wid = tid >> 6, lane = tid & 63;
    const int wr = wid >> 1, wc = wid & 1;
    const int row0 = blockIdx.y * 64, col0 = blockIdx.x * 64;
    const int lr = lane & 15, lk = lane >> 4;
    f32x4 acc[2][2] = {};
    const ushort_t* gB0 = WzT + (size_t)col0 * KZ;
    const int rs = tid >> 2, qs0 = tid & 3;
    const int qsw = qs0 ^ ((rs >> 1) & 3);
    for (int k0 = 0; k0 < KZ; k0 += 32) {
        const int koff = k0 >> 9;
        const int d0 = k0 & 511;
        const ushort_t* gA = node + (size_t)(row0 + koff) * FD + d0;
        __builtin_amdgcn_global_load_lds(
            (const __attribute__((address_space(1))) void*)(gA + (size_t)rs * FD + qsw * 8),
            (__attribute__((address_space(3))) void*)((char*)As + (wid << 10)),
            16, 0, 0);
        __builtin_amdgcn_global_load_lds(
            (const __attribute__((address_space(1))) void*)(gB0 + (size_t)rs * KZ + k0 + qsw * 8),
            (__attribute__((address_space(3))) void*)((char*)Bs + (wid << 10)),
            16, 0, 0);
        __syncthreads();
        bf16x8 af[2], bfr[2];
#pragma unroll
        for (int m = 0; m < 2; ++m) {
            const int fr = wr * 32 + m * 16 + lr;
            af[m] = *reinterpret_cast<const bf16x8*>(&As[fr * 32 + ((lk ^ ((fr >> 1) & 3)) << 3)]);
        }
#pragma unroll
        for (int n = 0; n < 2; ++n) {
            const int fr = wc * 32 + n * 16 + lr;
            bfr[n] = *reinterpret_cast<const bf16x8*>(&Bs[fr * 32 + ((lk ^ ((fr >> 1) & 3)) << 3)]);
        }
#pragma unroll
        for (int m = 0; m < 2; ++m)
#pragma unroll
            for (int n = 0; n < 2; ++n)
                acc[m][n] = __builtin_amdgcn_mfma_f32_16x16x32_bf16(af[m], bfr[n], acc[m][n], 0, 0, 0);
        __syncthreads();
    }
    // ---- fused pool epilogue ----
    const int bI = row0 >> 8;          // batch (64-row tile sits in one batch)
    const int nn0 = row0 & 255;        // n of first row
    __shared__ float snw[68];
    if (tid < 68) snw[tid] = (nn0 + tid < SL) ? nw[bI * SL + nn0 + tid] : 0.f;
    __syncthreads();
    float cmax[2];
#pragma unroll
    for (int n = 0; n < 2; ++n) {
        const int col = col0 + wc * 32 + n * 16 + lr;
        const int w = col >> 7;
        const int kw = w + 2;
        const float invk = (w == 0) ? 0.5f : (w == 1) ? (1.f / 3.f) : 0.25f;
        const float bf = ((w == 0) ? b2 : (w == 1) ? b3 : b4)[col & 127];
        const int nmax = SL - kw;      // valid n <= nmax
        float mx = -INFINITY;
#pragma unroll
        for (int m = 0; m < 2; ++m) {
            const int rbase = wr * 32 + m * 16 + lk * 4;
            const f32x4 vv = acc[m][n];
#pragma unroll
            for (int j = 0; j < 4; ++j) {
                const int rloc = rbase + j;
                if (nn0 + rloc <= nmax) {
                    float ws = 0.f;
                    for (int k = 0; k < kw; ++k) ws += snw[rloc + k];
                    mx = fmaxf(mx, ws * invk * vv[j] + bf);
                }
            }
        }
        mx = fmaxf(mx, __shfl_xor(mx, 16));
        mx = fmaxf(mx, __shfl_xor(mx, 32));
        cmax[n] = mx;
    }
    if (lane < 16) {
#pragma unroll
        for (int n = 0; n < 2; ++n) {
            const int col = col0 + wc * 32 + n * 16 + lr;
            pmaxp[((size_t)blockIdx.y * 2 + wr) * NZ + col] = cmax[n];
        }
    }
}

// ============================================================
// K4: edge scores. One 64-lane wave per (b, n), n in [0, 2SL).
// ============================================================
__global__ __launch_bounds__(256) void score_kernel(
    const ushort_t* __restrict__ node, const int* __restrict__ aspect_head,
    const int* __restrict__ deprel, const float* __restrict__ Ut,
    const float* __restrict__ v, const float* __restrict__ bilin_b,
    float* __restrict__ edge_score)
{
    const int g = blockIdx.x * 4 + (threadIdx.x >> 6);
    const int lane = threadIdx.x & 63;
    const int b = g >> 9;
    const int n = g & 511;
    const int d0 = lane * 8;
    typedef __attribute__((ext_vector_type(8))) unsigned short u16x8;
    float sum = 0.f;
    if (n < SL) {
        const int dr = deprel[b * SL + n];
        const int h = aspect_head[b * SL + n];
        const float* uc = Ut + (size_t)dr * 1024;
        const u16x8 nv = *reinterpret_cast<const u16x8*>(&node[((size_t)b * SL + n) * FD + d0]);
        if (h != 0) {
            const u16x8 dv = *reinterpret_cast<const u16x8*>(&node[((size_t)b * SL + (h - 1)) * FD + d0]);
#pragma unroll
            for (int i = 0; i < 8; ++i) sum += bf2f(dv[i]) * uc[d0 + i];
        }
#pragma unroll
        for (int i = 0; i < 8; ++i) sum += bf2f(nv[i]) * uc[FD + d0 + i];
    } else {
        const u16x8 nv = *reinterpret_cast<const u16x8*>(&node[((size_t)b * SL + (n - SL)) * FD + d0]);
#pragma unroll
        for (int i = 0; i < 8; ++i) sum += bf2f(nv[i]) * v[d0 + i];
    }
#pragma unroll
    for (int off = 32; off > 0; off >>= 1) sum += __shfl_xor(sum, off, 64);
    if (lane == 0) {
        const float sc = 1.f / (1.f + expf(-(sum + bilin_b[0])));
        edge_score[b * ES_STRIDE + 1 + n] = sc;
        if (n == 0) edge_score[b * ES_STRIDE] = 1.0f;
    }
}

// ============================================================
// K5: nw[b][s] = masked prod over path of edge_score; weight_norm[b] = sum_s
// ============================================================
__global__ __launch_bounds__(256) void nw_kernel(
    const float* __restrict__ edge_score, const int* __restrict__ path,
    const int* __restrict__ text_mask, const int* __restrict__ aspect_mask,
    float* __restrict__ nw, float* __restrict__ weight_norm)
{
    const int b = blockIdx.x, s = threadIdx.x;
    const float* es = edge_score + b * ES_STRIDE;
    const int* pp = path + ((size_t)b * SL + s) * PL;
    float p = 1.f;
#pragma unroll
    for (int l = 0; l < PL; ++l) p *= es[pp[l]];
    if (!(text_mask[b * SL + s] != 0 && aspect_mask[b * SL + s] == 0)) p = 0.f;
    nw[b * SL + s] = p;
    __shared__ float red[256];
    red[s] = p;
    __syncthreads();
    for (int off = 128; off > 0; off >>= 1) {
        if (s < off) red[s] += red[s + off];
        __syncthreads();
    }
    if (s == 0) weight_norm[b] = red[0];
}

// ============================================================
// K8: finish: sentence[b][c] = max over 8 partial rows; then fc_out.
// ============================================================
__global__ __launch_bounds__(384) void finish_kernel(
    const float* __restrict__ pmaxp, const float* __restrict__ W,
    const float* __restrict__ bias, float* __restrict__ out)
{
    const int b = blockIdx.x;
    const int t = threadIdx.x;     // 0..383
    const float* p = pmaxp + (size_t)b * 8 * NZ + t;
    float mx = -INFINITY;
#pragma unroll
    for (int i = 0; i < 8; ++i) mx = fmaxf(mx, p[(size_t)i * NZ]);
    __shared__ float sent[384];
    sent[t] = mx;
    __syncthreads();
    if (t < 3) {
        float acc = bias[t];
        for (int i = 0; i < 384; ++i) acc = fmaf(sent[i], W[i * 3 + t], acc);
        out[b * 3 + t] = acc;
    }
}

// ============================================================
extern "C" void kernel_launch(void* const* d_in, const int* in_sizes, int n_in,
                              void* d_out, int out_size, void* d_ws, size_t ws_size,
                              hipStream_t stream)
{
    const float* bert      = (const float*)d_in[0];
    const int*   wgi       = (const int*)d_in[1];
    const int*   pos       = (const int*)d_in[2];
    const int*   deprel    = (const int*)d_in[3];
    const int*   path      = (const int*)d_in[4];
    const int*   ahead     = (const int*)d_in[5];
    const int*   tmask     = (const int*)d_in[6];
    const int*   amask     = (const int*)d_in[7];
    const float* pos_emb   = (const float*)d_in[8];
    const float* dre_emb   = (const float*)d_in[9];
    const float* pd_emb    = (const float*)d_in[10];
    const float* ext_rel   = (const float*)d_in[11];
    const float* fc1_W     = (const float*)d_in[12];
    const float* fc1_b     = (const float*)d_in[13];
    const float* bilin_W   = (const float*)d_in[14];
    const float* bilin_b   = (const float*)d_in[15];
    const float* W2        = (const float*)d_in[16];
    const float* b2        = (const float*)d_in[17];
    const float* W3        = (const float*)d_in[18];
    const float* b3        = (const float*)d_in[19];
    const float* W4        = (const float*)d_in[20];
    const float* b4        = (const float*)d_in[21];
    const float* fco_W     = (const float*)d_in[22];
    const float* fco_b     = (const float*)d_in[23];
    float* out = (float*)d_out;

    // ---- workspace layout ----
    uint8_t* w = (uint8_t*)d_ws;
    ushort_t* node_in = (ushort_t*)w;                 // 14.68 MB
    size_t off = (size_t)MROWS * NIN * 2;
    ushort_t* node = (ushort_t*)(w + off); off += (size_t)(MROWS + 3) * FD * 2;
    ushort_t* Wt1  = (ushort_t*)(w + off); off += (size_t)FD * NIN * 2;
    ushort_t* WzT  = (ushort_t*)(w + off); off += (size_t)NZ * KZ * 2;
    float* Ut    = (float*)(w + off); off += (size_t)64 * 1024 * 4;
    float* vvec  = (float*)(w + off); off += FD * 4;
    float* es    = (float*)(w + off); off += (size_t)BSZ * ES_STRIDE * 4;
    float* nw    = (float*)(w + off); off += (size_t)BSZ * SL * 4;
    float* pmaxp = (float*)(w + off); off += (size_t)256 * NZ * 4;

    build_node_in<<<MROWS, 256, 0, stream>>>(bert, wgi, pos, path, pos_emb, pd_emb, node_in);
    prep_kernel<<<P4 / 256, 256, 0, stream>>>(bilin_W, dre_emb, ext_rel, fc1_W,
                                              W2, W3, W4, Ut, vvec, Wt1, WzT, node);

    gemm_node<<<dim3(FD / 64, MROWS / 128), 256, 0, stream>>>(node_in, Wt1, fc1_b, node);

    score_kernel<<<(BSZ * 2 * SL) / 4, 256, 0, stream>>>(
        node, ahead, deprel, Ut, vvec, bilin_b, es);

    nw_kernel<<<BSZ, 256, 0, stream>>>(es, path, tmask, amask, nw, out + 96);

    gemm_z_pool<<<dim3(NZ / 64, MROWS / 64), 256, 0, stream>>>(
        node, WzT, nw, b2, b3, b4, pmaxp);

    finish_kernel<<<BSZ, 384, 0, stream>>>(pmaxp, fco_W, fco_b, out);
}

// Round 6
// 112.317 us; speedup vs baseline: 3.6363x; 1.0348x over previous
//
#include <hip/hip_runtime.h>
#include <hip/hip_bf16.h>
#include <math.h>

// ---- problem constants ----
#define BSZ 32
#define SL 256
#define WPL 4
#define NP 320
#define WD 768
#define PD 64
#define RD 64
#define FD 512
#define PL 8
#define NF 128
#define NIN 896          // WD + 2*PD
#define ES_STRIDE 513    // 2*SL + 1
#define MROWS (BSZ * SL) // 8192
#define NZ 384           // 3 windows * NF
#define KZ 2048          // 4 * FD  (window-taps folded into K)

typedef __attribute__((ext_vector_type(8))) short bf16x8;
typedef __attribute__((ext_vector_type(4))) float f32x4;
typedef unsigned short ushort_t;
typedef __attribute__((ext_vector_type(4))) ushort_t u16x4;

__device__ __forceinline__ ushort_t f2bf(float x) {
    __hip_bfloat16 h = __float2bfloat16(x);
    return *reinterpret_cast<ushort_t*>(&h);
}
__device__ __forceinline__ float bf2f(ushort_t u) {
    return __uint_as_float(((unsigned)u) << 16);
}

// ============================================================
// K1 (merged setup): blocks [0,8192): node_in row build.
// blocks [8192, 8192+5128): prep (Ut, v, Wt1, WzT, node pad rows).
// ============================================================
#define P0 65536
#define P1 (P0 + 512)
#define P2 (P1 + FD * NIN)
#define P3 (P2 + NZ * KZ)
#define P4 (P3 + 3 * FD)
#define PREP_BLOCKS (P4 / 256)   // 5128
__global__ __launch_bounds__(256) void setup_kernel(
    const float* __restrict__ bert, const int* __restrict__ wgi,
    const int* __restrict__ pos, const int* __restrict__ path,
    const float* __restrict__ pos_emb, const float* __restrict__ pd_emb,
    const float* __restrict__ bilin_W, const float* __restrict__ deprel_emb,
    const float* __restrict__ ext_rel, const float* __restrict__ fc1_W,
    const float* __restrict__ W2, const float* __restrict__ W3,
    const float* __restrict__ W4,
    ushort_t* __restrict__ node_in,
    float* __restrict__ Ut, float* __restrict__ v,
    ushort_t* __restrict__ Wt1, ushort_t* __restrict__ WzT,
    ushort_t* __restrict__ node)
{
    const int tid = threadIdx.x;
    if (blockIdx.x < MROWS) {
        const int bs = blockIdx.x;
        const int b = bs >> 8;
        const int* gi = wgi + (size_t)bs * WPL;
        const int i0 = gi[0], i1 = gi[1], i2 = gi[2], i3 = gi[3];
        const int npc = (i0 != 0) + (i1 != 0) + (i2 != 0) + (i3 != 0);
        const float inv = 1.0f / (float)(npc > 1 ? npc : 1);
        ushort_t* out = node_in + (size_t)bs * NIN;
        if (tid < 192) {
            const float4* r0 = (const float4*)(bert + ((size_t)b * NP + (i0 - 1)) * WD);
            const float4* r1 = (const float4*)(bert + ((size_t)b * NP + (i1 - 1)) * WD);
            const float4* r2 = (const float4*)(bert + ((size_t)b * NP + (i2 - 1)) * WD);
            const float4* r3 = (const float4*)(bert + ((size_t)b * NP + (i3 - 1)) * WD);
            float4 s = make_float4(0.f, 0.f, 0.f, 0.f);
            if (i0) { float4 t = r0[tid]; s.x += t.x; s.y += t.y; s.z += t.z; s.w += t.w; }
            if (i1) { float4 t = r1[tid]; s.x += t.x; s.y += t.y; s.z += t.z; s.w += t.w; }
            if (i2) { float4 t = r2[tid]; s.x += t.x; s.y += t.y; s.z += t.z; s.w += t.w; }
            if (i3) { float4 t = r3[tid]; s.x += t.x; s.y += t.y; s.z += t.z; s.w += t.w; }
            u16x4 o;
            o[0] = f2bf(s.x * inv); o[1] = f2bf(s.y * inv);
            o[2] = f2bf(s.z * inv); o[3] = f2bf(s.w * inv);
            *reinterpret_cast<u16x4*>(&out[tid * 4]) = o;
        } else {
            const int e = tid - 192;   // 0..63
            out[WD + e] = f2bf(pos_emb[pos[bs] * PD + e]);
            const int* pp = path + (size_t)bs * PL;
            int pd = 0;
#pragma unroll
            for (int l = 0; l < PL; ++l) pd += (pp[l] != 0);
            out[WD + PD + e] = f2bf(pd_emb[pd * PD + e]);
        }
        return;
    }
    const int idx = (blockIdx.x - MROWS) * 256 + tid;
    if (idx < P0) {
        const int r = idx >> 10, d = idx & 1023;
        float s = 0.f;
#pragma unroll
        for (int j = 0; j < RD; ++j) s += bilin_W[d * RD + j] * deprel_emb[r * RD + j];
        Ut[idx] = s;
    } else if (idx < P1) {
        const int d = idx - P0;
        float s = 0.f;
#pragma unroll
        for (int j = 0; j < RD; ++j) s += bilin_W[d * RD + j] * ext_rel[j];
        v[d] = s;
    } else if (idx < P2) {
        const int j = idx - P1;
        const int k = j >> 9, n = j & 511;       // read coalesced over n
        Wt1[(size_t)n * NIN + k] = f2bf(fc1_W[(size_t)k * FD + n]);
    } else if (idx < P3) {
        const int j = idx - P2;
        const int kp = j / NZ, c = j - kp * NZ;  // read coalesced over c (f)
        const int w = c >> 7, f = c & 127;
        const int k = kp >> 9, d = kp & 511;
        const int kw = w + 2;
        float val = 0.f;
        if (k < kw) {
            const float* Wsrc = (w == 0) ? W2 : (w == 1) ? W3 : W4;
            val = Wsrc[((size_t)k * FD + d) * NF + f];
        }
        WzT[(size_t)c * KZ + kp] = f2bf(val);
    } else if (idx < P4) {
        const int j = idx - P3;
        node[(size_t)MROWS * FD + j] = 0;        // 3 zero pad rows
    }
}

// ============================================================
// K2: node = relu(node_in @ fc1_W + b).  BM=128 x BN=64, BK=64, 4 waves 2x2,
// wave = 64x32 (4x2 frags, 16 MFMA : 12 ds_read per iter).
// 8-chunk XOR swizzle (q ^= r&7) on src + read -> 2-way (free) LDS reads.
// grid (8, 64) = 512 blocks.
// ============================================================
__global__ __launch_bounds__(256) void gemm_node(
    const ushort_t* __restrict__ A,   // [M][NIN]
    const ushort_t* __restrict__ Bt,  // [FD][NIN]
    const float* __restrict__ bias,
    ushort_t* __restrict__ C)         // [M][FD]
{
    __shared__ ushort_t As[128 * 64];
    __shared__ ushort_t Bs[64 * 64];
    const int tid = threadIdx.x;
    const int wid = tid >> 6, lane = tid & 63;
    const int wr = wid >> 1, wc = wid & 1;
    const int row0 = blockIdx.y * 128, col0 = blockIdx.x * 64;
    const int lr = lane & 15, lk = lane >> 4;
    f32x4 acc[4][2] = {};
    const ushort_t* gA0 = A + (size_t)row0 * NIN;
    const ushort_t* gB0 = Bt + (size_t)col0 * NIN;
    for (int k0 = 0; k0 < NIN; k0 += 64) {
#pragma unroll
        for (int i = 0; i < 4; ++i) {
            const int c = i * 256 + (wid << 6) + lane;
            const int r = c >> 3, q = (c & 7) ^ (r & 7);
            __builtin_amdgcn_global_load_lds(
                (const __attribute__((address_space(1))) void*)(gA0 + (size_t)r * NIN + k0 + q * 8),
                (__attribute__((address_space(3))) void*)((char*)As + i * 4096 + (wid << 10)),
                16, 0, 0);
        }
#pragma unroll
        for (int i = 0; i < 2; ++i) {
            const int c = i * 256 + (wid << 6) + lane;
            const int r = c >> 3, q = (c & 7) ^ (r & 7);
            __builtin_amdgcn_global_load_lds(
                (const __attribute__((address_space(1))) void*)(gB0 + (size_t)r * NIN + k0 + q * 8),
                (__attribute__((address_space(3))) void*)((char*)Bs + i * 4096 + (wid << 10)),
                16, 0, 0);
        }
        __syncthreads();
        bf16x8 af[4][2], bfv[2][2];
#pragma unroll
        for (int m = 0; m < 4; ++m) {
            const int fr = wr * 64 + m * 16 + lr;
#pragma unroll
            for (int ks = 0; ks < 2; ++ks)
                af[m][ks] = *reinterpret_cast<const bf16x8*>(
                    &As[fr * 64 + ((((ks << 2) | lk) ^ (fr & 7)) << 3)]);
        }
#pragma unroll
        for (int n = 0; n < 2; ++n) {
            const int fr = wc * 32 + n * 16 + lr;
#pragma unroll
            for (int ks = 0; ks < 2; ++ks)
                bfv[n][ks] = *reinterpret_cast<const bf16x8*>(
                    &Bs[fr * 64 + ((((ks << 2) | lk) ^ (fr & 7)) << 3)]);
        }
#pragma unroll
        for (int ks = 0; ks < 2; ++ks)
#pragma unroll
            for (int m = 0; m < 4; ++m)
#pragma unroll
                for (int n = 0; n < 2; ++n)
                    acc[m][n] = __builtin_amdgcn_mfma_f32_16x16x32_bf16(
                        af[m][ks], bfv[n][ks], acc[m][n], 0, 0, 0);
        __syncthreads();
    }
#pragma unroll
    for (int n = 0; n < 2; ++n) {
        const int col = col0 + wc * 32 + n * 16 + lr;
        const float bv = bias[col];
#pragma unroll
        for (int m = 0; m < 4; ++m) {
            const int rb = row0 + wr * 64 + m * 16 + lk * 4;
            const f32x4 vv = acc[m][n];
#pragma unroll
            for (int j = 0; j < 4; ++j)
                C[(size_t)(rb + j) * FD + col] = f2bf(fmaxf(vv[j] + bv, 0.f));
        }
    }
}

// ============================================================
// K5: GEMM-Z + fused windowed-scale + max-pool.
// BM=128 x BN=64, BK=64, 4 waves 2x2, wave = 64x32.
// Per-col-tile K extent: Keff = ((col0>>7)+2)*512  (skips zero taps).
// grid (6, 64) = 384 blocks.  Epilogue -> pmaxp[128][NZ].
// ============================================================
__global__ __launch_bounds__(256) void gemm_z_pool(
    const ushort_t* __restrict__ node,  // [(MROWS+3)][FD]
    const ushort_t* __restrict__ WzT,   // [NZ][KZ]
    const float* __restrict__ nw,
    const float* __restrict__ b2, const float* __restrict__ b3,
    const float* __restrict__ b4,
    float* __restrict__ pmaxp)          // [128][NZ]
{
    __shared__ ushort_t As[128 * 64];
    __shared__ ushort_t Bs[64 * 64];
    const int tid = threadIdx.x;
    const int wid = tid >> 6, lane = tid & 63;
    const int wr = wid >> 1, wc = wid & 1;
    const int row0 = blockIdx.y * 128, col0 = blockIdx.x * 64;
    const int lr = lane & 15, lk = lane >> 4;
    f32x4 acc[4][2] = {};
    const ushort_t* gB0 = WzT + (size_t)col0 * KZ;
    const int Keff = ((col0 >> 7) + 2) * 512;
    for (int k0 = 0; k0 < Keff; k0 += 64) {
        const int koff = k0 >> 9;
        const int d0 = k0 & 511;
        const ushort_t* gA0 = node + (size_t)(row0 + koff) * FD + d0;
#pragma unroll
        for (int i = 0; i < 4; ++i) {
            const int c = i * 256 + (wid << 6) + lane;
            const int r = c >> 3, q = (c & 7) ^ (r & 7);
            __builtin_amdgcn_global_load_lds(
                (const __attribute__((address_space(1))) void*)(gA0 + (size_t)r * FD + q * 8),
                (__attribute__((address_space(3))) void*)((char*)As + i * 4096 + (wid << 10)),
                16, 0, 0);
        }
#pragma unroll
        for (int i = 0; i < 2; ++i) {
            const int c = i * 256 + (wid << 6) + lane;
            const int r = c >> 3, q = (c & 7) ^ (r & 7);
            __builtin_amdgcn_global_load_lds(
                (const __attribute__((address_space(1))) void*)(gB0 + (size_t)r * KZ + k0 + q * 8),
                (__attribute__((address_space(3))) void*)((char*)Bs + i * 4096 + (wid << 10)),
                16, 0, 0);
        }
        __syncthreads();
        bf16x8 af[4][2], bfv[2][2];
#pragma unroll
        for (int m = 0; m < 4; ++m) {
            const int fr = wr * 64 + m * 16 + lr;
#pragma unroll
            for (int ks = 0; ks < 2; ++ks)
                af[m][ks] = *reinterpret_cast<const bf16x8*>(
                    &As[fr * 64 + ((((ks << 2) | lk) ^ (fr & 7)) << 3)]);
        }
#pragma unroll
        for (int n = 0; n < 2; ++n) {
            const int fr = wc * 32 + n * 16 + lr;
#pragma unroll
            for (int ks = 0; ks < 2; ++ks)
                bfv[n][ks] = *reinterpret_cast<const bf16x8*>(
                    &Bs[fr * 64 + ((((ks << 2) | lk) ^ (fr & 7)) << 3)]);
        }
#pragma unroll
        for (int ks = 0; ks < 2; ++ks)
#pragma unroll
            for (int m = 0; m < 4; ++m)
#pragma unroll
                for (int n = 0; n < 2; ++n)
                    acc[m][n] = __builtin_amdgcn_mfma_f32_16x16x32_bf16(
                        af[m][ks], bfv[n][ks], acc[m][n], 0, 0, 0);
        __syncthreads();
    }
    // ---- fused pool epilogue ----
    const int bI = row0 >> 8;          // batch (128-row tile sits in one batch)
    const int nn0 = row0 & 255;
    __shared__ float snw[132];
    if (tid < 132) snw[tid] = (nn0 + tid < SL) ? nw[bI * SL + nn0 + tid] : 0.f;
    __syncthreads();
    float cmax[2];
#pragma unroll
    for (int n = 0; n < 2; ++n) {
        const int col = col0 + wc * 32 + n * 16 + lr;
        const int w = col >> 7;
        const int kw = w + 2;
        const float invk = (w == 0) ? 0.5f : (w == 1) ? (1.f / 3.f) : 0.25f;
        const float bf = ((w == 0) ? b2 : (w == 1) ? b3 : b4)[col & 127];
        const int nmax = SL - kw;
        float mx = -INFINITY;
#pragma unroll
        for (int m = 0; m < 4; ++m) {
            const int rbase = wr * 64 + m * 16 + lk * 4;
            const f32x4 vv = acc[m][n];
#pragma unroll
            for (int j = 0; j < 4; ++j) {
                const int rloc = rbase + j;
                if (nn0 + rloc <= nmax) {
                    float ws = 0.f;
                    for (int k = 0; k < kw; ++k) ws += snw[rloc + k];
                    mx = fmaxf(mx, ws * invk * vv[j] + bf);
                }
            }
        }
        mx = fmaxf(mx, __shfl_xor(mx, 16));
        mx = fmaxf(mx, __shfl_xor(mx, 32));
        cmax[n] = mx;
    }
    if (lane < 16) {
#pragma unroll
        for (int n = 0; n < 2; ++n) {
            const int col = col0 + wc * 32 + n * 16 + lr;
            pmaxp[((size_t)blockIdx.y * 2 + wr) * NZ + col] = cmax[n];
        }
    }
}

// ============================================================
// K3: edge scores. One 64-lane wave per (b, n), n in [0, 2SL).
// ============================================================
__global__ __launch_bounds__(256) void score_kernel(
    const ushort_t* __restrict__ node, const int* __restrict__ aspect_head,
    const int* __restrict__ deprel, const float* __restrict__ Ut,
    const float* __restrict__ v, const float* __restrict__ bilin_b,
    float* __restrict__ edge_score)
{
    const int g = blockIdx.x * 4 + (threadIdx.x >> 6);
    const int lane = threadIdx.x & 63;
    const int b = g >> 9;
    const int n = g & 511;
    const int d0 = lane * 8;
    typedef __attribute__((ext_vector_type(8))) unsigned short u16x8;
    float sum = 0.f;
    if (n < SL) {
        const int dr = deprel[b * SL + n];
        const int h = aspect_head[b * SL + n];
        const float* uc = Ut + (size_t)dr * 1024;
        const u16x8 nv = *reinterpret_cast<const u16x8*>(&node[((size_t)b * SL + n) * FD + d0]);
        if (h != 0) {
            const u16x8 dv = *reinterpret_cast<const u16x8*>(&node[((size_t)b * SL + (h - 1)) * FD + d0]);
#pragma unroll
            for (int i = 0; i < 8; ++i) sum += bf2f(dv[i]) * uc[d0 + i];
        }
#pragma unroll
        for (int i = 0; i < 8; ++i) sum += bf2f(nv[i]) * uc[FD + d0 + i];
    } else {
        const u16x8 nv = *reinterpret_cast<const u16x8*>(&node[((size_t)b * SL + (n - SL)) * FD + d0]);
#pragma unroll
        for (int i = 0; i < 8; ++i) sum += bf2f(nv[i]) * v[d0 + i];
    }
#pragma unroll
    for (int off = 32; off > 0; off >>= 1) sum += __shfl_xor(sum, off, 64);
    if (lane == 0) {
        const float sc = 1.f / (1.f + expf(-(sum + bilin_b[0])));
        edge_score[b * ES_STRIDE + 1 + n] = sc;
        if (n == 0) edge_score[b * ES_STRIDE] = 1.0f;
    }
}

// ============================================================
// K4: nw[b][s] = masked prod over path of edge_score; weight_norm[b] = sum_s
// ============================================================
__global__ __launch_bounds__(256) void nw_kernel(
    const float* __restrict__ edge_score, const int* __restrict__ path,
    const int* __restrict__ text_mask, const int* __restrict__ aspect_mask,
    float* __restrict__ nw, float* __restrict__ weight_norm)
{
    const int b = blockIdx.x, s = threadIdx.x;
    const float* es = edge_score + b * ES_STRIDE;
    const int* pp = path + ((size_t)b * SL + s) * PL;
    float p = 1.f;
#pragma unroll
    for (int l = 0; l < PL; ++l) p *= es[pp[l]];
    if (!(text_mask[b * SL + s] != 0 && aspect_mask[b * SL + s] == 0)) p = 0.f;
    nw[b * SL + s] = p;
    __shared__ float red[256];
    red[s] = p;
    __syncthreads();
    for (int off = 128; off > 0; off >>= 1) {
        if (s < off) red[s] += red[s + off];
        __syncthreads();
    }
    if (s == 0) weight_norm[b] = red[0];
}

// ============================================================
// K6: finish: sentence[b][c] = max over 4 partial rows; then fc_out.
// ============================================================
__global__ __launch_bounds__(384) void finish_kernel(
    const float* __restrict__ pmaxp, const float* __restrict__ W,
    const float* __restrict__ bias, float* __restrict__ out)
{
    const int b = blockIdx.x;
    const int t = threadIdx.x;     // 0..383
    const float* p = pmaxp + (size_t)b * 4 * NZ + t;
    float mx = -INFINITY;
#pragma unroll
    for (int i = 0; i < 4; ++i) mx = fmaxf(mx, p[(size_t)i * NZ]);
    __shared__ float sent[384];
    sent[t] = mx;
    __syncthreads();
    if (t < 3) {
        float acc = bias[t];
        for (int i = 0; i < 384; ++i) acc = fmaf(sent[i], W[i * 3 + t], acc);
        out[b * 3 + t] = acc;
    }
}

// ============================================================
extern "C" void kernel_launch(void* const* d_in, const int* in_sizes, int n_in,
                              void* d_out, int out_size, void* d_ws, size_t ws_size,
                              hipStream_t stream)
{
    const float* bert      = (const float*)d_in[0];
    const int*   wgi       = (const int*)d_in[1];
    const int*   pos       = (const int*)d_in[2];
    const int*   deprel    = (const int*)d_in[3];
    const int*   path      = (const int*)d_in[4];
    const int*   ahead     = (const int*)d_in[5];
    const int*   tmask     = (const int*)d_in[6];
    const int*   amask     = (const int*)d_in[7];
    const float* pos_emb   = (const float*)d_in[8];
    const float* dre_emb   = (const float*)d_in[9];
    const float* pd_emb    = (const float*)d_in[10];
    const float* ext_rel   = (const float*)d_in[11];
    const float* fc1_W     = (const float*)d_in[12];
    const float* fc1_b     = (const float*)d_in[13];
    const float* bilin_W   = (const float*)d_in[14];
    const float* bilin_b   = (const float*)d_in[15];
    const float* W2        = (const float*)d_in[16];
    const float* b2        = (const float*)d_in[17];
    const float* W3        = (const float*)d_in[18];
    const float* b3        = (const float*)d_in[19];
    const float* W4        = (const float*)d_in[20];
    const float* b4        = (const float*)d_in[21];
    const float* fco_W     = (const float*)d_in[22];
    const float* fco_b     = (const float*)d_in[23];
    float* out = (float*)d_out;

    // ---- workspace layout ----
    uint8_t* w = (uint8_t*)d_ws;
    ushort_t* node_in = (ushort_t*)w;                 // 14.68 MB
    size_t off = (size_t)MROWS * NIN * 2;
    ushort_t* node = (ushort_t*)(w + off); off += (size_t)(MROWS + 3) * FD * 2;
    ushort_t* Wt1  = (ushort_t*)(w + off); off += (size_t)FD * NIN * 2;
    ushort_t* WzT  = (ushort_t*)(w + off); off += (size_t)NZ * KZ * 2;
    float* Ut    = (float*)(w + off); off += (size_t)64 * 1024 * 4;
    float* vvec  = (float*)(w + off); off += FD * 4;
    float* es    = (float*)(w + off); off += (size_t)BSZ * ES_STRIDE * 4;
    float* nw    = (float*)(w + off); off += (size_t)BSZ * SL * 4;
    float* pmaxp = (float*)(w + off); off += (size_t)128 * NZ * 4;

    setup_kernel<<<MROWS + PREP_BLOCKS, 256, 0, stream>>>(
        bert, wgi, pos, path, pos_emb, pd_emb,
        bilin_W, dre_emb, ext_rel, fc1_W, W2, W3, W4,
        node_in, Ut, vvec, Wt1, WzT, node);

    gemm_node<<<dim3(FD / 64, MROWS / 128), 256, 0, stream>>>(node_in, Wt1, fc1_b, node);

    score_kernel<<<(BSZ * 2 * SL) / 4, 256, 0, stream>>>(
        node, ahead, deprel, Ut, vvec, bilin_b, es);

    nw_kernel<<<BSZ, 256, 0, stream>>>(es, path, tmask, amask, nw, out + 96);

    gemm_z_pool<<<dim3(NZ / 64, MROWS / 128), 256, 0, stream>>>(
        node, WzT, nw, b2, b3, b4, pmaxp);

    finish_kernel<<<BSZ, 384, 0, stream>>>(pmaxp, fco_W, fco_b, out);
}